// Round 10
// baseline (602.244 us; speedup 1.0000x reference)
//
#include <hip/hip_runtime.h>

#define HID 128
#define NGRAPH 512
#define NLAYERS 3
#define BN_EPS 1e-5f
#define NPB 256          // nodes per bucket (CSR build)
#define EB 4096          // edges per build block

typedef __attribute__((ext_vector_type(8))) short bf16x8;
typedef __attribute__((ext_vector_type(4))) float f32x4;
typedef __attribute__((ext_vector_type(2))) float f32x2;

__device__ inline unsigned short f2bf(float x) {
    union { float f; unsigned u; } v; v.f = x;
    unsigned r = v.u + 0x7FFFu + ((v.u >> 16) & 1u);
    return (unsigned short)(r >> 16);
}
__device__ inline float bf2f(unsigned short b) {
    union { float f; unsigned u; } v; v.u = ((unsigned)b) << 16; return v.f;
}
// 1 dword (2 packed bf16) -> f32x2 {lo, hi}
__device__ inline f32x2 bfp(unsigned u) {
    union { unsigned q; float f; } lo, hi;
    lo.q = u << 16; hi.q = u & 0xFFFF0000u;
    f32x2 r; r[0] = lo.f; r[1] = hi.f; return r;
}

// ---------------------------------------------------------------------------
// prep (one launch): zero sliced-stats+gsum | W split+transpose | x->bf16 | ecount
// ---------------------------------------------------------------------------
__global__ void k_prep(float* __restrict__ ssliced, float* __restrict__ gsum,
                       const float4* __restrict__ x4, ushort* __restrict__ xb, int total4,
                       const float* __restrict__ W1, ushort* __restrict__ w1h, ushort* __restrict__ w1l,
                       const float* __restrict__ W2, ushort* __restrict__ w2h, ushort* __restrict__ w2l,
                       int wtotal, int xblocks,
                       const int* __restrict__ dst, int E, int* __restrict__ blkcnt) {
    __shared__ int hist[512];
    int b = blockIdx.x, t = threadIdx.x;
    if (b < 768) {
        if (b < 24) ssliced[b * 256 + t] = 0.0f;   // 8 slices x 3 layers x 256
        gsum[b * 256 + t] = 0.0f;
    } else if (b < 1152) {
        int gid = (b - 768) * 256 + t;
        const float* W; ushort *Wh, *Wl; int e;
        if (gid < wtotal) { W = W1; Wh = w1h; Wl = w1l; e = gid; }
        else              { W = W2; Wh = w2h; Wl = w2l; e = gid - wtotal; }
        if (e < wtotal) {
            int l = e >> 14, rem = e & 16383, k = rem >> 7, n = rem & 127;
            float v = W[e];
            ushort hi = f2bf(v);
            ushort lo = f2bf(v - bf2f(hi));
            int o = (l << 14) + (n << 7) + k;
            Wh[o] = hi; Wl[o] = lo;
        }
    } else if (b < 1152 + xblocks) {
        int i = (b - 1152) * 256 + t;
        if (i < total4) {
            float4 v = x4[i];
            uint2 p;
            p.x = ((unsigned)f2bf(v.y) << 16) | f2bf(v.x);
            p.y = ((unsigned)f2bf(v.w) << 16) | f2bf(v.z);
            ((uint2*)xb)[i] = p;
        }
    } else {
        // edge count histogram
        int b2 = b - (1152 + xblocks);
        hist[t] = 0; hist[t + 256] = 0;
        __syncthreads();
        int base = b2 * EB;
        #pragma unroll
        for (int i = 0; i < 16; ++i) {
            int e = base + i * 256 + t;
            if (e < E) atomicAdd(&hist[dst[e] >> 8], 1);
        }
        __syncthreads();
        blkcnt[b2 * 512 + t]       = hist[t];
        blkcnt[b2 * 512 + t + 256] = hist[t + 256];
    }
}

// ---------------------------------------------------------------------------
// CSR build, deterministic two-level (NO global atomics)
// ---------------------------------------------------------------------------
__global__ __launch_bounds__(256) void k_btot_reduce(const int* __restrict__ blkcnt,
                                                     int eblk, int* __restrict__ tot) {
    __shared__ int sh[256];
    int b = blockIdx.x;       // bucket
    int t = threadIdx.x;
    int s = 0;
    for (int j = t; j < eblk; j += 256) s += blkcnt[j * 512 + b];
    sh[t] = s;
    __syncthreads();
    #pragma unroll
    for (int k = 128; k > 0; k >>= 1) {
        if (t < k) sh[t] += sh[t + k];
        __syncthreads();
    }
    if (t == 0) tot[b] = sh[0];
}

__global__ __launch_bounds__(512) void k_bscan(const int* __restrict__ tot, int nb, int E,
                                               int* __restrict__ bbase, int* __restrict__ rowptrN) {
    __shared__ int sh[512];
    int t = threadIdx.x;                       // 512 threads
    sh[t] = (t < nb) ? tot[t] : 0;
    __syncthreads();
    #pragma unroll
    for (int s = 1; s < 512; s <<= 1) {
        int v = (t >= s) ? sh[t - s] : 0;
        __syncthreads();
        sh[t] += v;
        __syncthreads();
    }
    if (t < nb) bbase[t] = (t == 0) ? 0 : sh[t - 1];   // exclusive
    if (t == 0) { bbase[nb] = E; *rowptrN = E; }
}

// per-column exclusive scan of blkcnt (bucket b), parallel Hillis-Steele.
__global__ __launch_bounds__(512) void k_colscan(int* __restrict__ blkcnt, int eblk,
                                                 const int* __restrict__ bbase) {
    __shared__ int sh[512];
    int t = threadIdx.x;
    int b = blockIdx.x;
    sh[t] = (t < eblk) ? blkcnt[t * 512 + b] : 0;
    __syncthreads();
    #pragma unroll
    for (int s = 1; s < 512; s <<= 1) {
        int v = (t >= s) ? sh[t - s] : 0;
        __syncthreads();
        sh[t] += v;
        __syncthreads();
    }
    int excl = (t == 0) ? 0 : sh[t - 1];
    if (t < eblk) blkcnt[t * 512 + b] = bbase[b] + excl;
}

__global__ __launch_bounds__(256) void k_bscatter(const int* __restrict__ src,
                                                  const int* __restrict__ dst, int E,
                                                  const int* __restrict__ blkcnt,
                                                  unsigned* __restrict__ pairs) {
    __shared__ int hist[512];    // local cursor (starts at 0)
    __shared__ int lbase[512];   // absolute base for this block's chunk per bucket
    int t = threadIdx.x;
    hist[t] = 0; hist[t + 256] = 0;
    lbase[t]       = blkcnt[blockIdx.x * 512 + t];
    lbase[t + 256] = blkcnt[blockIdx.x * 512 + t + 256];
    __syncthreads();
    int base = blockIdx.x * EB;
    #pragma unroll
    for (int i = 0; i < 16; ++i) {
        int e = base + i * 256 + t;
        if (e < E) {
            int d = dst[e];
            int b = d >> 8;
            int pos = lbase[b] + atomicAdd(&hist[b], 1);
            pairs[pos] = ((unsigned)(d & 255) << 24) | (unsigned)src[e];
        }
    }
}

__global__ __launch_bounds__(256) void k_bbuild(const unsigned* __restrict__ pairs,
                                                const int* __restrict__ bbase, int N,
                                                int* __restrict__ rowptr, int* __restrict__ csr) {
    __shared__ int cnt[256];
    __shared__ int off[256];
    int t = threadIdx.x;
    int b = blockIdx.x;
    int base = bbase[b], bcount = bbase[b + 1] - base;
    cnt[t] = 0;
    __syncthreads();
    for (int i = t; i < bcount; i += 256) atomicAdd(&cnt[pairs[base + i] >> 24], 1);
    __syncthreads();
    off[t] = cnt[t];
    __syncthreads();
    for (int s = 1; s < 256; s <<= 1) {
        int v = (t >= s) ? off[t - s] : 0;
        __syncthreads();
        off[t] += v;
        __syncthreads();
    }
    int excl = (t == 0) ? 0 : off[t - 1];
    int node = b * NPB + t;
    if (node < N) rowptr[node] = base + excl;
    cnt[t] = excl;                      // becomes per-node cursor
    __syncthreads();
    for (int i = t; i < bcount; i += 256) {
        unsigned p = pairs[base + i];
        int dl = p >> 24;
        int pos = base + atomicAdd(&cnt[dl], 1);
        csr[pos] = (int)(p & 0xFFFFFFu);
    }
}

// ---------------------------------------------------------------------------
// part 1: pure gather+BN -> z0.  R10: launch_bounds (256,8) — R9 measured
// VGPR=40 (< the 64 cap), occupancy 51% was launch-bounds-capped, not
// register-capped; 8 blocks/CU allows 32 waves/CU of independent gathers.
// ---------------------------------------------------------------------------
__global__ __launch_bounds__(256, 8) void k_agg(
        const int* __restrict__ rowptr, const int* __restrict__ csr_src,
        const uint2* __restrict__ hinb,
        const float* __restrict__ prev_stats,      // null for layer 0; else sum|sq (256)
        const float* __restrict__ g_row, const float* __restrict__ be_row,
        const float* __restrict__ eps_gin, int layer,
        ushort* __restrict__ z0out, int N) {
    const int t = threadIdx.x;
    const int lane = t & 63;
    const int wv = t >> 6;
    const int q = lane >> 4;           // 0..3: row within the wave
    const int f = lane & 15;           // uint4 lane (8 bf16 features) within row

    f32x2 scv2[4], shv2[4];
    if (prev_stats) {
        float invn = 1.0f / (float)N;
        #pragma unroll
        for (int d = 0; d < 4; ++d) {
            #pragma unroll
            for (int h = 0; h < 2; ++h) {
                int fi = f * 8 + d * 2 + h;
                float mu = prev_stats[fi] * invn;
                float var = prev_stats[128 + fi] * invn - mu * mu;
                float inv = rsqrtf(var + BN_EPS);
                float scj = g_row[fi] * inv;
                scv2[d][h] = scj; shv2[d][h] = be_row[fi] - mu * scj;
            }
        }
    } else {
        #pragma unroll
        for (int d = 0; d < 4; ++d) { scv2[d] = (f32x2){1.f, 1.f}; shv2[d] = (f32x2){0.f, 0.f}; }
    }
    float e1 = 1.0f + eps_gin[layer];
    const uint4* hin4 = (const uint4*)hinb;

    int r = blockIdx.x * 16 + wv * 4 + q;     // global row
    f32x2 a2[4];
    #pragma unroll
    for (int d = 0; d < 4; ++d) a2[d] = (f32x2){0.f, 0.f};
    float cdeg = 0.f;
    if (r < N) {
        int beg = rowptr[r], end = rowptr[r + 1];
        uint4 hv = hin4[(size_t)r * 16 + f];
        a2[0] = e1 * bfp(hv.x); a2[1] = e1 * bfp(hv.y);
        a2[2] = e1 * bfp(hv.z); a2[3] = e1 * bfp(hv.w);
        int p = beg;
        // ---- full batches: NO masks ----
        for (; p + 8 <= end; p += 8) {
            int s0 = csr_src[p],     s1 = csr_src[p + 1], s2 = csr_src[p + 2], s3 = csr_src[p + 3];
            int s4 = csr_src[p + 4], s5 = csr_src[p + 5], s6 = csr_src[p + 6], s7 = csr_src[p + 7];
            uint4 v0 = hin4[(size_t)s0 * 16 + f];
            uint4 v1 = hin4[(size_t)s1 * 16 + f];
            uint4 v2 = hin4[(size_t)s2 * 16 + f];
            uint4 v3 = hin4[(size_t)s3 * 16 + f];
            uint4 v4 = hin4[(size_t)s4 * 16 + f];
            uint4 v5 = hin4[(size_t)s5 * 16 + f];
            uint4 v6 = hin4[(size_t)s6 * 16 + f];
            uint4 v7 = hin4[(size_t)s7 * 16 + f];
            a2[0] += ((bfp(v0.x) + bfp(v1.x)) + (bfp(v2.x) + bfp(v3.x)))
                   + ((bfp(v4.x) + bfp(v5.x)) + (bfp(v6.x) + bfp(v7.x)));
            a2[1] += ((bfp(v0.y) + bfp(v1.y)) + (bfp(v2.y) + bfp(v3.y)))
                   + ((bfp(v4.y) + bfp(v5.y)) + (bfp(v6.y) + bfp(v7.y)));
            a2[2] += ((bfp(v0.z) + bfp(v1.z)) + (bfp(v2.z) + bfp(v3.z)))
                   + ((bfp(v4.z) + bfp(v5.z)) + (bfp(v6.z) + bfp(v7.z)));
            a2[3] += ((bfp(v0.w) + bfp(v1.w)) + (bfp(v2.w) + bfp(v3.w)))
                   + ((bfp(v4.w) + bfp(v5.w)) + (bfp(v6.w) + bfp(v7.w)));
        }
        // ---- single partial tail: clamp + dword-level masks ----
        if (p < end) {
            int last = end - 1;
            int c1 = min(p + 1, last), c2 = min(p + 2, last), c3 = min(p + 3, last);
            int c4 = min(p + 4, last), c5 = min(p + 5, last), c6 = min(p + 6, last);
            int s0 = csr_src[p],  s1 = csr_src[c1], s2 = csr_src[c2], s3 = csr_src[c3];
            int s4 = csr_src[c4], s5 = csr_src[c5], s6 = csr_src[c6];
            uint4 v0 = hin4[(size_t)s0 * 16 + f];
            uint4 v1 = hin4[(size_t)s1 * 16 + f];
            uint4 v2 = hin4[(size_t)s2 * 16 + f];
            uint4 v3 = hin4[(size_t)s3 * 16 + f];
            uint4 v4 = hin4[(size_t)s4 * 16 + f];
            uint4 v5 = hin4[(size_t)s5 * 16 + f];
            uint4 v6 = hin4[(size_t)s6 * 16 + f];
            int rem = end - p;           // 1..7
            unsigned m1 = (rem > 1) ? 0xFFFFFFFFu : 0u;
            unsigned m2 = (rem > 2) ? 0xFFFFFFFFu : 0u;
            unsigned m3 = (rem > 3) ? 0xFFFFFFFFu : 0u;
            unsigned m4 = (rem > 4) ? 0xFFFFFFFFu : 0u;
            unsigned m5 = (rem > 5) ? 0xFFFFFFFFu : 0u;
            unsigned m6 = (rem > 6) ? 0xFFFFFFFFu : 0u;
            a2[0] += ((bfp(v0.x) + bfp(v1.x & m1)) + (bfp(v2.x & m2) + bfp(v3.x & m3)))
                   + ((bfp(v4.x & m4) + bfp(v5.x & m5)) + bfp(v6.x & m6));
            a2[1] += ((bfp(v0.y) + bfp(v1.y & m1)) + (bfp(v2.y & m2) + bfp(v3.y & m3)))
                   + ((bfp(v4.y & m4) + bfp(v5.y & m5)) + bfp(v6.y & m6));
            a2[2] += ((bfp(v0.z) + bfp(v1.z & m1)) + (bfp(v2.z & m2) + bfp(v3.z & m3)))
                   + ((bfp(v4.z & m4) + bfp(v5.z & m5)) + bfp(v6.z & m6));
            a2[3] += ((bfp(v0.w) + bfp(v1.w & m1)) + (bfp(v2.w & m2) + bfp(v3.w & m3)))
                   + ((bfp(v4.w & m4) + bfp(v5.w & m5)) + bfp(v6.w & m6));
        }
        cdeg = e1 + (float)(end - beg);
    }
    f32x2 rr2[4];
    #pragma unroll
    for (int d = 0; d < 4; ++d) rr2[d] = scv2[d] * a2[d] + cdeg * shv2[d];
    uint4 ph;
    ph.x = ((unsigned)f2bf(rr2[0][1]) << 16) | f2bf(rr2[0][0]);
    ph.y = ((unsigned)f2bf(rr2[1][1]) << 16) | f2bf(rr2[1][0]);
    ph.z = ((unsigned)f2bf(rr2[2][1]) << 16) | f2bf(rr2[2][0]);
    ph.w = ((unsigned)f2bf(rr2[3][1]) << 16) | f2bf(rr2[3][0]);
    if (r < N) ((uint4*)z0out)[(size_t)r * 16 + f] = ph;
}

// ---------------------------------------------------------------------------
// part 2: dense MLP over z0.  R10: PERSISTENT grid (512 blocks = 2/CU),
// tiles strided by gridDim — weights hoisted ONCE per block and reused
// across ~3 tiles (R9 reloaded them per 64-row tile).
// ---------------------------------------------------------------------------
__global__ __launch_bounds__(256, 2) void k_mlp_dense(
        const uint4* __restrict__ z0, int layer, const int* __restrict__ batch,
        const ushort* __restrict__ w1h, const ushort* __restrict__ w1l,
        const float* __restrict__ b1,
        const ushort* __restrict__ w2h, const ushort* __restrict__ w2l,
        const float* __restrict__ b2,
        ushort* __restrict__ Hout, float* __restrict__ stat_sl,
        float* __restrict__ gsum, int N, int ntiles) {
    __shared__ __align__(16) ushort smem[8192];    // 16 KB
    const int t = threadIdx.x;
    const int lane = t & 63;
    const int wv = t >> 6;
    const int li = lane & 15;
    const int kq = lane >> 4;
    const int n0 = wv * 32;
    const int swz = (li & 7) * 4;

    // ---- hoist all weight fragments into registers (32 x 16B loads, once) ----
    bf16x8 w1hr[8], w1lr[8], w2hr[8], w2lr[8];
    #pragma unroll
    for (int ch = 0; ch < 2; ++ch)
        #pragma unroll
        for (int ks = 0; ks < 2; ++ks)
            #pragma unroll
            for (int nt = 0; nt < 2; ++nt) {
                int i = ch * 4 + ks * 2 + nt;
                size_t wo = (size_t)(n0 + nt * 16 + li) * 128 + (ch * 64 + ks * 32 + kq * 8);
                w1hr[i] = *(const bf16x8*)&w1h[wo];
                w1lr[i] = *(const bf16x8*)&w1l[wo];
                w2hr[i] = *(const bf16x8*)&w2h[wo];
                w2lr[i] = *(const bf16x8*)&w2l[wo];
            }
    float bz0 = b1[n0 + li], bz1 = b1[n0 + 16 + li];
    float bb0 = b2[n0 + li], bb1 = b2[n0 + 16 + li];

    for (int tile = blockIdx.x; tile < ntiles; tile += gridDim.x) {
        const int row0 = tile * 64;

        // ---- stage z0 tile -> LDS (swizzled), zero-fill rows >= N ----
        {
            const uint4 zz = {0u, 0u, 0u, 0u};
            #pragma unroll
            for (int i = 0; i < 4; ++i) {
                int idx = i * 256 + t;             // 0..1023
                int r = idx >> 4, f = idx & 15;
                uint4 v = (row0 + r < N) ? z0[(size_t)(row0 + r) * 16 + f] : zz;
                ((uint4*)smem)[r * 16 + (f ^ (r & 7))] = v;
            }
        }
        __syncthreads();

        f32x4 acc[4][2];
        #pragma unroll
        for (int i = 0; i < 4; ++i) {
            acc[i][0] = (f32x4){0.f, 0.f, 0.f, 0.f};
            acc[i][1] = (f32x4){0.f, 0.f, 0.f, 0.f};
        }

        // ---------------- GEMM1: z1 = z0 @ W1 (registers only for W) ----------------
        #pragma unroll
        for (int ch = 0; ch < 2; ++ch) {
            #pragma unroll
            for (int ks = 0; ks < 2; ++ks) {
                int kcol = ch * 8 + ks * 4 + kq;            // u4 col 0..15
                #pragma unroll
                for (int mt = 0; mt < 4; ++mt) {
                    int r = mt * 16 + li;
                    int hw = (r * 16 + (kcol ^ (li & 7))) * 8;
                    bf16x8 ah = *(const bf16x8*)&smem[hw];
                    #pragma unroll
                    for (int nt = 0; nt < 2; ++nt) {
                        int i = ch * 4 + ks * 2 + nt;
                        acc[mt][nt] = __builtin_amdgcn_mfma_f32_16x16x32_bf16(ah, w1hr[i], acc[mt][nt], 0, 0, 0);
                        acc[mt][nt] = __builtin_amdgcn_mfma_f32_16x16x32_bf16(ah, w1lr[i], acc[mt][nt], 0, 0, 0);
                    }
                }
            }
        }

        // ---- z1 = relu(acc + b1) -> Z overlay (A-layout, bf16, swizzled) ----
        __syncthreads();                    // all GEMM1 A-reads done before overwrite
        #pragma unroll
        for (int mt = 0; mt < 4; ++mt) {
            #pragma unroll
            for (int nt = 0; nt < 2; ++nt) {
                int c = n0 + nt * 16 + li;
                int dk = c >> 1;
                int halfbase = (dk >> 5) * 32;
                int dlow = dk & 31;
                int codd = c & 1;
                float bias = nt ? bz1 : bz0;
                #pragma unroll
                for (int reg = 0; reg < 4; ++reg) {
                    int r = mt * 16 + kq * 4 + reg;
                    float v = fmaxf(acc[mt][nt][reg] + bias, 0.f);
                    int us = (r * 64 + halfbase + (dlow ^ ((r & 7) * 4))) * 2 + codd;
                    smem[us] = f2bf(v);
                }
            }
        }
        #pragma unroll
        for (int i = 0; i < 4; ++i) {
            acc[i][0] = (f32x4){0.f, 0.f, 0.f, 0.f};
            acc[i][1] = (f32x4){0.f, 0.f, 0.f, 0.f};
        }
        __syncthreads();

        // ---------------- GEMM2: z2 = z1 @ W2 (registers only for W) ----------------
        #pragma unroll
        for (int ch = 0; ch < 2; ++ch) {
            #pragma unroll
            for (int ks = 0; ks < 2; ++ks) {
                int aoff = (ks * 16 + kq * 4) ^ swz;        // dwords
                #pragma unroll
                for (int mt = 0; mt < 4; ++mt) {
                    int idx = ((mt * 16 + li) * 64 + ch * 32 + aoff) * 2;
                    bf16x8 ah = *(const bf16x8*)&smem[idx];
                    #pragma unroll
                    for (int nt = 0; nt < 2; ++nt) {
                        int i = ch * 4 + ks * 2 + nt;
                        acc[mt][nt] = __builtin_amdgcn_mfma_f32_16x16x32_bf16(ah, w2hr[i], acc[mt][nt], 0, 0, 0);
                        acc[mt][nt] = __builtin_amdgcn_mfma_f32_16x16x32_bf16(ah, w2lr[i], acc[mt][nt], 0, 0, 0);
                    }
                }
            }
        }

        // ---- epilogue: bias+relu; z2 -> LDS (row-major); BN stats; pool sums ----
        int btr[4][4];
        #pragma unroll
        for (int mt = 0; mt < 4; ++mt)
            #pragma unroll
            for (int reg = 0; reg < 4; ++reg) {
                int grow = row0 + mt * 16 + kq * 4 + reg;
                btr[mt][reg] = (grow < N) ? batch[grow] : -1;
            }
        __syncthreads();                    // all GEMM2 z1-reads done before overwrite
        float s0 = 0.f, q0 = 0.f, s1 = 0.f, q1 = 0.f;
        #pragma unroll
        for (int mt = 0; mt < 4; ++mt) {
            #pragma unroll
            for (int reg = 0; reg < 4; ++reg) {
                int r = mt * 16 + kq * 4 + reg;
                float v0 = fmaxf(acc[mt][0][reg] + bb0, 0.f);
                float v1 = fmaxf(acc[mt][1][reg] + bb1, 0.f);
                smem[r * 128 + n0 + li]      = f2bf(v0);
                smem[r * 128 + n0 + 16 + li] = f2bf(v1);
                if (btr[mt][reg] >= 0) {
                    s0 += v0; q0 += v0 * v0; s1 += v1; q1 += v1 * v1;
                }
            }
        }
        __syncthreads();
        // coalesced store: 64 rows x 16 uint4 (full 64B lines)
        {
            int valid = N - row0; if (valid > 64) valid = 64;
            int tot = valid * 16;
            for (int i = t; i < tot; i += 256) {
                int r = i >> 4, c = i & 15;
                ((uint4*)&Hout[(size_t)(row0 + r) * HID])[c] = ((const uint4*)smem)[r * 16 + c];
            }
        }
        s0 += __shfl_xor(s0, 16); s0 += __shfl_xor(s0, 32);
        q0 += __shfl_xor(q0, 16); q0 += __shfl_xor(q0, 32);
        s1 += __shfl_xor(s1, 16); s1 += __shfl_xor(s1, 32);
        q1 += __shfl_xor(q1, 16); q1 += __shfl_xor(q1, 32);
        if (kq == 0) {
            float* ss = stat_sl + (blockIdx.x & 7) * 768;   // slice: sum[0..127] | sq[128..255]
            unsafeAtomicAdd(&ss[n0 + li], s0);
            unsafeAtomicAdd(&ss[128 + n0 + li], q0);
            unsafeAtomicAdd(&ss[n0 + 16 + li], s1);
            unsafeAtomicAdd(&ss[128 + n0 + 16 + li], q1);
        }
        // per-graph raw sums (affine applied later in k_mlp)
        int lastr = N - 1; if (lastr > row0 + 63) lastr = row0 + 63;
        int g_lo = batch[row0], g_hi = batch[lastr];
        int loff = layer * HID;
        for (int g = g_lo; g <= g_hi; ++g) {
            float p0 = 0.f, p1 = 0.f;
            #pragma unroll
            for (int mt = 0; mt < 4; ++mt)
                #pragma unroll
                for (int reg = 0; reg < 4; ++reg) {
                    if (btr[mt][reg] == g) {
                        p0 += fmaxf(acc[mt][0][reg] + bb0, 0.f);
                        p1 += fmaxf(acc[mt][1][reg] + bb1, 0.f);
                    }
                }
            p0 += __shfl_xor(p0, 16); p0 += __shfl_xor(p0, 32);
            p1 += __shfl_xor(p1, 16); p1 += __shfl_xor(p1, 32);
            if (kq == 0) {
                unsafeAtomicAdd(&gsum[(size_t)g * 384 + loff + n0 + li], p0);
                unsafeAtomicAdd(&gsum[(size_t)g * 384 + loff + n0 + 16 + li], p1);
            }
        }
        __syncthreads();   // smem fully consumed before next tile's stage
    }
}

// fold 8 stat slices for one layer into the final stats buffer
__global__ __launch_bounds__(256) void k_sfold(const float* __restrict__ sliced,
                                               float* __restrict__ out) {
    int t = threadIdx.x;     // 256: sum[0..127] | sq[128..255]
    float s = 0.f;
    #pragma unroll
    for (int k = 0; k < 8; ++k) s += sliced[k * 768 + t];
    out[t] = s;
}

// ---------------------------------------------------------------------------
// final MLP: 8 graphs/block — w1 value loaded once per k, used 8x.
// (R9: 512 blocks x 196KB w1 = 100 MB of L2/L3 traffic; now 64 x 196KB.)
// ---------------------------------------------------------------------------
__global__ __launch_bounds__(128) void k_mlp(const int* __restrict__ batch, int N,
                     const float* __restrict__ gsum, const float* __restrict__ stats,
                     const float* __restrict__ gamma, const float* __restrict__ beta,
                     const float* __restrict__ w1, const float* __restrict__ b1,
                     const float* __restrict__ w2, const float* __restrict__ b2,
                     float* __restrict__ out) {
    __shared__ float gl[8][384];
    __shared__ float hh[8][128];
    int g0 = blockIdx.x * 8, t = threadIdx.x;   // 128 threads, 8 graphs
    float invn = 1.0f / (float)N;
    // BN affine per feature (same for all graphs) — compute once
    float sc[NLAYERS], sh[NLAYERS];
    #pragma unroll
    for (int l = 0; l < NLAYERS; ++l) {
        float mu = stats[l * 256 + t] * invn;
        float var = stats[l * 256 + 128 + t] * invn - mu * mu;
        float inv = rsqrtf(var + BN_EPS);
        sc[l] = gamma[l * HID + t] * inv;
        sh[l] = beta[l * HID + t] - mu * sc[l];
    }
    for (int j = 0; j < 8; ++j) {
        int g = g0 + j;
        int start, end;
        { int lo = 0, hi = N; while (lo < hi) { int m = (lo + hi) >> 1; if (batch[m] < g) lo = m + 1; else hi = m; } start = lo; }
        { int lo = start, hi = N; while (lo < hi) { int m = (lo + hi) >> 1; if (batch[m] < g + 1) lo = m + 1; else hi = m; } end = lo; }
        float cnt = (float)(end - start);
        float invc = 1.0f / fmaxf(cnt, 1.0f);
        #pragma unroll
        for (int l = 0; l < NLAYERS; ++l)
            gl[j][l * 128 + t] = (gsum[(size_t)g * 384 + l * 128 + t] * sc[l] + sh[l] * cnt) * invc;
    }
    __syncthreads();
    float acc[8];
    #pragma unroll
    for (int j = 0; j < 8; ++j) acc[j] = b1[t];
    for (int k = 0; k < 384; ++k) {
        float wv = w1[k * HID + t];
        #pragma unroll
        for (int j = 0; j < 8; ++j) acc[j] = fmaf(gl[j][k], wv, acc[j]);
    }
    #pragma unroll
    for (int j = 0; j < 8; ++j) hh[j][t] = fmaxf(acc[j], 0.f);
    __syncthreads();
    if (t < 80) {
        int j = t / 10, o = t % 10;
        float a2 = b2[o];
        for (int k = 0; k < 128; ++k) a2 = fmaf(hh[j][k], w2[k * 10 + o], a2);
        out[(g0 + j) * 10 + o] = a2;
    }
}

// ---------------------------------------------------------------------------
extern "C" void kernel_launch(void* const* d_in, const int* in_sizes, int n_in,
                              void* d_out, int out_size, void* d_ws, size_t ws_size,
                              hipStream_t stream) {
    const float* x     = (const float*)d_in[0];
    const int*   ei    = (const int*)d_in[1];
    const int*   batch = (const int*)d_in[2];
    const float* W1    = (const float*)d_in[3];
    const float* b1    = (const float*)d_in[4];
    const float* W2    = (const float*)d_in[5];
    const float* b2    = (const float*)d_in[6];
    const float* gamma = (const float*)d_in[7];
    const float* beta  = (const float*)d_in[8];
    const float* epsg  = (const float*)d_in[9];
    const float* l1w   = (const float*)d_in[10];
    const float* l1b   = (const float*)d_in[11];
    const float* l2w   = (const float*)d_in[12];
    const float* l2b   = (const float*)d_in[13];

    const int N = in_sizes[0] / HID;
    const int E = in_sizes[1] / 2;
    const int* src = ei;
    const int* dst = ei + E;
    const int nb = (N + NPB - 1) / NPB;           // <= 512
    const int eblk = (E + EB - 1) / EB;           // <= 512

    float* w = (float*)d_ws;
    const size_t NF = (size_t)N * HID;
    ushort* xb    = (ushort*)(w + NF);                       // x as bf16 (NF ushorts)
    ushort* hb[3] = { xb + NF, xb + 2 * NF, xb + 3 * NF };   // layer outputs, bf16
    ushort* z0buf = xb + 4 * NF;                             // aggregated input (NF ushorts)
    float* stats  = w + 4 * NF;       // 3*256 final (folded)
    float* sliced = stats + 768;      // 8 slices x 3 layers x 256
    float* gsum   = sliced + 6144;    // 512 * 384 (per-graph raw sums)
    int*   rowptr = (int*)(gsum + (size_t)NGRAPH * 384);     // N + 1
    int*   csr    = rowptr + N + 1;                          // E
    int*   bbase  = csr + E;                                 // nb + 1
    int*   btot   = bbase + nb + 2;                          // nb (bucket totals)
    ushort* wt  = (ushort*)(((uintptr_t)(btot + nb + 1) + 15) & ~(uintptr_t)15);
    ushort* w1h = wt;
    ushort* w1l = wt + 49152;
    ushort* w2h = wt + 98304;
    ushort* w2l = wt + 147456;

    unsigned* pairs  = (unsigned*)w;                // E uints (CSR build only)
    int*      blkcnt = (int*)(w + 2 * 1024 * 1024); // eblk*512 (CSR build only)

    const int total4 = (int)(NF / 4);
    const int xblocks = (total4 + 255) / 256;
    const int prep_blocks = 1152 + xblocks + eblk;
    k_prep<<<prep_blocks, 256, 0, stream>>>(sliced, gsum, (const float4*)x, xb, total4,
                                            W1, w1h, w1l, W2, w2h, w2l, NLAYERS * HID * HID,
                                            xblocks, dst, E, blkcnt);

    // ---- build CSR (deterministic, no global atomics) ----
    k_btot_reduce<<<nb, 256, 0, stream>>>(blkcnt, eblk, btot);
    k_bscan<<<1, 512, 0, stream>>>(btot, nb, E, bbase, rowptr + N);
    k_colscan<<<nb, 512, 0, stream>>>(blkcnt, eblk, bbase);
    k_bscatter<<<eblk, 256, 0, stream>>>(src, dst, E, blkcnt, pairs);
    k_bbuild<<<nb, 256, 0, stream>>>(pairs, bbase, N, rowptr, csr);

    const int ntiles = (N + 63) / 64;
    for (int l = 0; l < NLAYERS; ++l) {
        const ushort* hin = (l == 0) ? xb : hb[l - 1];
        const float* pstats = (l == 0) ? nullptr : (stats + (l - 1) * 256);
        const float* grow_  = gamma + (l == 0 ? 0 : (l - 1)) * HID;
        const float* brow_  = beta  + (l == 0 ? 0 : (l - 1)) * HID;

        k_agg<<<(N + 15) / 16, 256, 0, stream>>>(
            rowptr, csr, (const uint2*)hin, pstats, grow_, brow_, epsg, l, z0buf, N);

        k_mlp_dense<<<512, 256, 0, stream>>>(
            (const uint4*)z0buf, l, batch,
            w1h + (size_t)l * 16384, w1l + (size_t)l * 16384, b1 + l * HID,
            w2h + (size_t)l * 16384, w2l + (size_t)l * 16384, b2 + l * HID,
            hb[l], sliced + l * 256, gsum, N, ntiles);

        k_sfold<<<1, 256, 0, stream>>>(sliced + l * 256, stats + l * 256);
    }

    k_mlp<<<NGRAPH / 8, 128, 0, stream>>>(batch, N, gsum, stats, gamma, beta,
                                          l1w, l1b, l2w, l2b, (float*)d_out);
}

// Round 11
// 562.275 us; speedup vs baseline: 1.0711x; 1.0711x over previous
//
#include <hip/hip_runtime.h>

#define HID 128
#define NGRAPH 512
#define NLAYERS 3
#define BN_EPS 1e-5f
#define NPB 256          // nodes per bucket (CSR build)
#define EB 4096          // edges per build block

typedef __attribute__((ext_vector_type(8))) short bf16x8;
typedef __attribute__((ext_vector_type(4))) float f32x4;
typedef __attribute__((ext_vector_type(2))) float f32x2;

__device__ inline unsigned short f2bf(float x) {
    union { float f; unsigned u; } v; v.f = x;
    unsigned r = v.u + 0x7FFFu + ((v.u >> 16) & 1u);
    return (unsigned short)(r >> 16);
}
__device__ inline float bf2f(unsigned short b) {
    union { float f; unsigned u; } v; v.u = ((unsigned)b) << 16; return v.f;
}
// 1 dword (2 packed bf16) -> f32x2 {lo, hi}
__device__ inline f32x2 bfp(unsigned u) {
    union { unsigned q; float f; } lo, hi;
    lo.q = u << 16; hi.q = u & 0xFFFF0000u;
    f32x2 r; r[0] = lo.f; r[1] = hi.f; return r;
}

// ---------------------------------------------------------------------------
// prep (one launch): W split+transpose | x->bf16 | ecount (+btot atomics).
// Zeroing of sliced/gsum/btot is done by hipMemsetAsync before this launch.
// ---------------------------------------------------------------------------
__global__ void k_prep(const float4* __restrict__ x4, ushort* __restrict__ xb, int total4,
                       const float* __restrict__ W1, ushort* __restrict__ w1h, ushort* __restrict__ w1l,
                       const float* __restrict__ W2, ushort* __restrict__ w2h, ushort* __restrict__ w2l,
                       int wtotal, int xblocks,
                       const int* __restrict__ dst, int E, int* __restrict__ blkcnt,
                       int* __restrict__ btot) {
    __shared__ int hist[512];
    int b = blockIdx.x, t = threadIdx.x;
    if (b < 384) {
        int gid = b * 256 + t;
        const float* W; ushort *Wh, *Wl; int e;
        if (gid < wtotal) { W = W1; Wh = w1h; Wl = w1l; e = gid; }
        else              { W = W2; Wh = w2h; Wl = w2l; e = gid - wtotal; }
        if (e < wtotal) {
            int l = e >> 14, rem = e & 16383, k = rem >> 7, n = rem & 127;
            float v = W[e];
            ushort hi = f2bf(v);
            ushort lo = f2bf(v - bf2f(hi));
            int o = (l << 14) + (n << 7) + k;
            Wh[o] = hi; Wl[o] = lo;
        }
    } else if (b < 384 + xblocks) {
        int i = (b - 384) * 256 + t;
        if (i < total4) {
            float4 v = x4[i];
            uint2 p;
            p.x = ((unsigned)f2bf(v.y) << 16) | f2bf(v.x);
            p.y = ((unsigned)f2bf(v.w) << 16) | f2bf(v.z);
            ((uint2*)xb)[i] = p;
        }
    } else {
        // edge count histogram + bucket-total atomics (int, order-independent)
        int b2 = b - (384 + xblocks);
        hist[t] = 0; hist[t + 256] = 0;
        __syncthreads();
        int base = b2 * EB;
        #pragma unroll
        for (int i = 0; i < 16; ++i) {
            int e = base + i * 256 + t;
            if (e < E) atomicAdd(&hist[dst[e] >> 8], 1);
        }
        __syncthreads();
        blkcnt[b2 * 512 + t]       = hist[t];
        blkcnt[b2 * 512 + t + 256] = hist[t + 256];
        if (hist[t])       atomicAdd(&btot[t], hist[t]);
        if (hist[t + 256]) atomicAdd(&btot[t + 256], hist[t + 256]);
    }
}

// ---------------------------------------------------------------------------
// CSR build, deterministic two-level (NO global atomics in ordering-sensitive
// steps; btot comes from integer atomics which are order-independent)
// ---------------------------------------------------------------------------
__global__ __launch_bounds__(512) void k_bscan(const int* __restrict__ tot, int nb, int E,
                                               int* __restrict__ bbase, int* __restrict__ rowptrN) {
    __shared__ int sh[512];
    int t = threadIdx.x;                       // 512 threads
    sh[t] = (t < nb) ? tot[t] : 0;
    __syncthreads();
    #pragma unroll
    for (int s = 1; s < 512; s <<= 1) {
        int v = (t >= s) ? sh[t - s] : 0;
        __syncthreads();
        sh[t] += v;
        __syncthreads();
    }
    if (t < nb) bbase[t] = (t == 0) ? 0 : sh[t - 1];   // exclusive
    if (t == 0) { bbase[nb] = E; *rowptrN = E; }
}

// per-column exclusive scan of blkcnt (bucket b), parallel Hillis-Steele.
__global__ __launch_bounds__(512) void k_colscan(int* __restrict__ blkcnt, int eblk,
                                                 const int* __restrict__ bbase) {
    __shared__ int sh[512];
    int t = threadIdx.x;
    int b = blockIdx.x;
    sh[t] = (t < eblk) ? blkcnt[t * 512 + b] : 0;
    __syncthreads();
    #pragma unroll
    for (int s = 1; s < 512; s <<= 1) {
        int v = (t >= s) ? sh[t - s] : 0;
        __syncthreads();
        sh[t] += v;
        __syncthreads();
    }
    int excl = (t == 0) ? 0 : sh[t - 1];
    if (t < eblk) blkcnt[t * 512 + b] = bbase[b] + excl;
}

__global__ __launch_bounds__(256) void k_bscatter(const int* __restrict__ src,
                                                  const int* __restrict__ dst, int E,
                                                  const int* __restrict__ blkcnt,
                                                  unsigned* __restrict__ pairs) {
    __shared__ int hist[512];    // local cursor (starts at 0)
    __shared__ int lbase[512];   // absolute base for this block's chunk per bucket
    int t = threadIdx.x;
    hist[t] = 0; hist[t + 256] = 0;
    lbase[t]       = blkcnt[blockIdx.x * 512 + t];
    lbase[t + 256] = blkcnt[blockIdx.x * 512 + t + 256];
    __syncthreads();
    int base = blockIdx.x * EB;
    #pragma unroll
    for (int i = 0; i < 16; ++i) {
        int e = base + i * 256 + t;
        if (e < E) {
            int d = dst[e];
            int b = d >> 8;
            int pos = lbase[b] + atomicAdd(&hist[b], 1);
            pairs[pos] = ((unsigned)(d & 255) << 24) | (unsigned)src[e];
        }
    }
}

__global__ __launch_bounds__(256) void k_bbuild(const unsigned* __restrict__ pairs,
                                                const int* __restrict__ bbase, int N,
                                                int* __restrict__ rowptr, int* __restrict__ csr) {
    __shared__ int cnt[256];
    __shared__ int off[256];
    int t = threadIdx.x;
    int b = blockIdx.x;
    int base = bbase[b], bcount = bbase[b + 1] - base;
    cnt[t] = 0;
    __syncthreads();
    for (int i = t; i < bcount; i += 256) atomicAdd(&cnt[pairs[base + i] >> 24], 1);
    __syncthreads();
    off[t] = cnt[t];
    __syncthreads();
    for (int s = 1; s < 256; s <<= 1) {
        int v = (t >= s) ? off[t - s] : 0;
        __syncthreads();
        off[t] += v;
        __syncthreads();
    }
    int excl = (t == 0) ? 0 : off[t - 1];
    int node = b * NPB + t;
    if (node < N) rowptr[node] = base + excl;
    cnt[t] = excl;                      // becomes per-node cursor
    __syncthreads();
    for (int i = t; i < bcount; i += 256) {
        unsigned p = pairs[base + i];
        int dl = p >> 24;
        int pos = base + atomicAdd(&cnt[dl], 1);
        csr[pos] = (int)(p & 0xFFFFFFu);
    }
}

// ---------------------------------------------------------------------------
// part 1: pure gather+BN -> z0.  R11: back to (256,6) — R10's (256,8) cut the
// VGPR cap to 64 and SPILLED the 8-deep gather batch (WRITE_SIZE 25->99 MB
// = scratch).  (256,6) keeps 40 VGPRs spill-free; occupancy ~51% is the
// spill-free sweet spot.  Stat slices folded per-block into LDS (k_sfold
// kernels eliminated).
// ---------------------------------------------------------------------------
__global__ __launch_bounds__(256, 6) void k_agg(
        const int* __restrict__ rowptr, const int* __restrict__ csr_src,
        const uint2* __restrict__ hinb,
        const float* __restrict__ prev_sliced,     // null for layer 0; else 8 slices (stride 768)
        const float* __restrict__ g_row, const float* __restrict__ be_row,
        const float* __restrict__ eps_gin, int layer,
        ushort* __restrict__ z0out, int N) {
    __shared__ float sfold[256];
    const int t = threadIdx.x;
    const int lane = t & 63;
    const int wv = t >> 6;
    const int q = lane >> 4;           // 0..3: row within the wave
    const int f = lane & 15;           // uint4 lane (8 bf16 features) within row

    if (prev_sliced) {
        float s = 0.f;
        #pragma unroll
        for (int k = 0; k < 8; ++k) s += prev_sliced[k * 768 + t];
        sfold[t] = s;                  // sum[0..127] | sq[128..255]
        __syncthreads();
    }

    f32x2 scv2[4], shv2[4];
    if (prev_sliced) {
        float invn = 1.0f / (float)N;
        #pragma unroll
        for (int d = 0; d < 4; ++d) {
            #pragma unroll
            for (int h = 0; h < 2; ++h) {
                int fi = f * 8 + d * 2 + h;
                float mu = sfold[fi] * invn;
                float var = sfold[128 + fi] * invn - mu * mu;
                float inv = rsqrtf(var + BN_EPS);
                float scj = g_row[fi] * inv;
                scv2[d][h] = scj; shv2[d][h] = be_row[fi] - mu * scj;
            }
        }
    } else {
        #pragma unroll
        for (int d = 0; d < 4; ++d) { scv2[d] = (f32x2){1.f, 1.f}; shv2[d] = (f32x2){0.f, 0.f}; }
    }
    float e1 = 1.0f + eps_gin[layer];
    const uint4* hin4 = (const uint4*)hinb;

    int r = blockIdx.x * 16 + wv * 4 + q;     // global row
    f32x2 a2[4];
    #pragma unroll
    for (int d = 0; d < 4; ++d) a2[d] = (f32x2){0.f, 0.f};
    float cdeg = 0.f;
    if (r < N) {
        int beg = rowptr[r], end = rowptr[r + 1];
        uint4 hv = hin4[(size_t)r * 16 + f];
        a2[0] = e1 * bfp(hv.x); a2[1] = e1 * bfp(hv.y);
        a2[2] = e1 * bfp(hv.z); a2[3] = e1 * bfp(hv.w);
        int p = beg;
        // ---- full batches: NO masks ----
        for (; p + 8 <= end; p += 8) {
            int s0 = csr_src[p],     s1 = csr_src[p + 1], s2 = csr_src[p + 2], s3 = csr_src[p + 3];
            int s4 = csr_src[p + 4], s5 = csr_src[p + 5], s6 = csr_src[p + 6], s7 = csr_src[p + 7];
            uint4 v0 = hin4[(size_t)s0 * 16 + f];
            uint4 v1 = hin4[(size_t)s1 * 16 + f];
            uint4 v2 = hin4[(size_t)s2 * 16 + f];
            uint4 v3 = hin4[(size_t)s3 * 16 + f];
            uint4 v4 = hin4[(size_t)s4 * 16 + f];
            uint4 v5 = hin4[(size_t)s5 * 16 + f];
            uint4 v6 = hin4[(size_t)s6 * 16 + f];
            uint4 v7 = hin4[(size_t)s7 * 16 + f];
            a2[0] += ((bfp(v0.x) + bfp(v1.x)) + (bfp(v2.x) + bfp(v3.x)))
                   + ((bfp(v4.x) + bfp(v5.x)) + (bfp(v6.x) + bfp(v7.x)));
            a2[1] += ((bfp(v0.y) + bfp(v1.y)) + (bfp(v2.y) + bfp(v3.y)))
                   + ((bfp(v4.y) + bfp(v5.y)) + (bfp(v6.y) + bfp(v7.y)));
            a2[2] += ((bfp(v0.z) + bfp(v1.z)) + (bfp(v2.z) + bfp(v3.z)))
                   + ((bfp(v4.z) + bfp(v5.z)) + (bfp(v6.z) + bfp(v7.z)));
            a2[3] += ((bfp(v0.w) + bfp(v1.w)) + (bfp(v2.w) + bfp(v3.w)))
                   + ((bfp(v4.w) + bfp(v5.w)) + (bfp(v6.w) + bfp(v7.w)));
        }
        // ---- single partial tail: clamp + dword-level masks ----
        if (p < end) {
            int last = end - 1;
            int c1 = min(p + 1, last), c2 = min(p + 2, last), c3 = min(p + 3, last);
            int c4 = min(p + 4, last), c5 = min(p + 5, last), c6 = min(p + 6, last);
            int s0 = csr_src[p],  s1 = csr_src[c1], s2 = csr_src[c2], s3 = csr_src[c3];
            int s4 = csr_src[c4], s5 = csr_src[c5], s6 = csr_src[c6];
            uint4 v0 = hin4[(size_t)s0 * 16 + f];
            uint4 v1 = hin4[(size_t)s1 * 16 + f];
            uint4 v2 = hin4[(size_t)s2 * 16 + f];
            uint4 v3 = hin4[(size_t)s3 * 16 + f];
            uint4 v4 = hin4[(size_t)s4 * 16 + f];
            uint4 v5 = hin4[(size_t)s5 * 16 + f];
            uint4 v6 = hin4[(size_t)s6 * 16 + f];
            int rem = end - p;           // 1..7
            unsigned m1 = (rem > 1) ? 0xFFFFFFFFu : 0u;
            unsigned m2 = (rem > 2) ? 0xFFFFFFFFu : 0u;
            unsigned m3 = (rem > 3) ? 0xFFFFFFFFu : 0u;
            unsigned m4 = (rem > 4) ? 0xFFFFFFFFu : 0u;
            unsigned m5 = (rem > 5) ? 0xFFFFFFFFu : 0u;
            unsigned m6 = (rem > 6) ? 0xFFFFFFFFu : 0u;
            a2[0] += ((bfp(v0.x) + bfp(v1.x & m1)) + (bfp(v2.x & m2) + bfp(v3.x & m3)))
                   + ((bfp(v4.x & m4) + bfp(v5.x & m5)) + bfp(v6.x & m6));
            a2[1] += ((bfp(v0.y) + bfp(v1.y & m1)) + (bfp(v2.y & m2) + bfp(v3.y & m3)))
                   + ((bfp(v4.y & m4) + bfp(v5.y & m5)) + bfp(v6.y & m6));
            a2[2] += ((bfp(v0.z) + bfp(v1.z & m1)) + (bfp(v2.z & m2) + bfp(v3.z & m3)))
                   + ((bfp(v4.z & m4) + bfp(v5.z & m5)) + bfp(v6.z & m6));
            a2[3] += ((bfp(v0.w) + bfp(v1.w & m1)) + (bfp(v2.w & m2) + bfp(v3.w & m3)))
                   + ((bfp(v4.w & m4) + bfp(v5.w & m5)) + bfp(v6.w & m6));
        }
        cdeg = e1 + (float)(end - beg);
    }
    f32x2 rr2[4];
    #pragma unroll
    for (int d = 0; d < 4; ++d) rr2[d] = scv2[d] * a2[d] + cdeg * shv2[d];
    uint4 ph;
    ph.x = ((unsigned)f2bf(rr2[0][1]) << 16) | f2bf(rr2[0][0]);
    ph.y = ((unsigned)f2bf(rr2[1][1]) << 16) | f2bf(rr2[1][0]);
    ph.z = ((unsigned)f2bf(rr2[2][1]) << 16) | f2bf(rr2[2][0]);
    ph.w = ((unsigned)f2bf(rr2[3][1]) << 16) | f2bf(rr2[3][0]);
    if (r < N) ((uint4*)z0out)[(size_t)r * 16 + f] = ph;
}

// ---------------------------------------------------------------------------
// part 2: dense MLP over z0 (64 rows/block) — R9 form: weights hoisted into
// registers once per block (32 x 16B loads, one wait), launch_bounds(256,2).
// BN-stat atomics 8-way sliced by blockIdx&7.
// ---------------------------------------------------------------------------
__global__ __launch_bounds__(256, 2) void k_mlp_dense(
        const uint4* __restrict__ z0, int layer, const int* __restrict__ batch,
        const ushort* __restrict__ w1h, const ushort* __restrict__ w1l,
        const float* __restrict__ b1,
        const ushort* __restrict__ w2h, const ushort* __restrict__ w2l,
        const float* __restrict__ b2,
        ushort* __restrict__ Hout, float* __restrict__ stat_sl,
        float* __restrict__ gsum, int N) {
    __shared__ __align__(16) ushort smem[8192];    // 16 KB
    const int t = threadIdx.x;
    const int lane = t & 63;
    const int wv = t >> 6;
    const int li = lane & 15;
    const int kq = lane >> 4;
    const int n0 = wv * 32;
    const int row0 = blockIdx.x * 64;
    const int swz = (li & 7) * 4;

    // ---- hoist all weight fragments into registers (32 x 16B loads) ----
    bf16x8 w1hr[8], w1lr[8], w2hr[8], w2lr[8];
    #pragma unroll
    for (int ch = 0; ch < 2; ++ch)
        #pragma unroll
        for (int ks = 0; ks < 2; ++ks)
            #pragma unroll
            for (int nt = 0; nt < 2; ++nt) {
                int i = ch * 4 + ks * 2 + nt;
                size_t wo = (size_t)(n0 + nt * 16 + li) * 128 + (ch * 64 + ks * 32 + kq * 8);
                w1hr[i] = *(const bf16x8*)&w1h[wo];
                w1lr[i] = *(const bf16x8*)&w1l[wo];
                w2hr[i] = *(const bf16x8*)&w2h[wo];
                w2lr[i] = *(const bf16x8*)&w2l[wo];
            }

    // ---- stage z0 tile -> LDS (swizzled), zero-fill rows >= N ----
    {
        const uint4 zz = {0u, 0u, 0u, 0u};
        #pragma unroll
        for (int i = 0; i < 4; ++i) {
            int idx = i * 256 + t;             // 0..1023
            int r = idx >> 4, f = idx & 15;
            uint4 v = (row0 + r < N) ? z0[(size_t)(row0 + r) * 16 + f] : zz;
            ((uint4*)smem)[r * 16 + (f ^ (r & 7))] = v;
        }
    }
    __syncthreads();

    f32x4 acc[4][2];
    #pragma unroll
    for (int i = 0; i < 4; ++i) {
        acc[i][0] = (f32x4){0.f, 0.f, 0.f, 0.f};
        acc[i][1] = (f32x4){0.f, 0.f, 0.f, 0.f};
    }

    // ---------------- GEMM1: z1 = z0 @ W1 (registers only for W) ----------------
    #pragma unroll
    for (int ch = 0; ch < 2; ++ch) {
        #pragma unroll
        for (int ks = 0; ks < 2; ++ks) {
            int kcol = ch * 8 + ks * 4 + kq;            // u4 col 0..15
            #pragma unroll
            for (int mt = 0; mt < 4; ++mt) {
                int r = mt * 16 + li;
                int hw = (r * 16 + (kcol ^ (li & 7))) * 8;
                bf16x8 ah = *(const bf16x8*)&smem[hw];
                #pragma unroll
                for (int nt = 0; nt < 2; ++nt) {
                    int i = ch * 4 + ks * 2 + nt;
                    acc[mt][nt] = __builtin_amdgcn_mfma_f32_16x16x32_bf16(ah, w1hr[i], acc[mt][nt], 0, 0, 0);
                    acc[mt][nt] = __builtin_amdgcn_mfma_f32_16x16x32_bf16(ah, w1lr[i], acc[mt][nt], 0, 0, 0);
                }
            }
        }
    }

    // ---- z1 = relu(acc + b1) -> Z overlay (A-layout, bf16, swizzled) ----
    float bz0 = b1[n0 + li], bz1 = b1[n0 + 16 + li];
    __syncthreads();                    // all GEMM1 A-reads done before overwrite
    #pragma unroll
    for (int mt = 0; mt < 4; ++mt) {
        #pragma unroll
        for (int nt = 0; nt < 2; ++nt) {
            int c = n0 + nt * 16 + li;
            int dk = c >> 1;
            int halfbase = (dk >> 5) * 32;
            int dlow = dk & 31;
            int codd = c & 1;
            float bias = nt ? bz1 : bz0;
            #pragma unroll
            for (int reg = 0; reg < 4; ++reg) {
                int r = mt * 16 + kq * 4 + reg;
                float v = fmaxf(acc[mt][nt][reg] + bias, 0.f);
                int us = (r * 64 + halfbase + (dlow ^ ((r & 7) * 4))) * 2 + codd;
                smem[us] = f2bf(v);
            }
        }
    }
    #pragma unroll
    for (int i = 0; i < 4; ++i) {
        acc[i][0] = (f32x4){0.f, 0.f, 0.f, 0.f};
        acc[i][1] = (f32x4){0.f, 0.f, 0.f, 0.f};
    }
    __syncthreads();

    // ---------------- GEMM2: z2 = z1 @ W2 (registers only for W) ----------------
    #pragma unroll
    for (int ch = 0; ch < 2; ++ch) {
        #pragma unroll
        for (int ks = 0; ks < 2; ++ks) {
            int aoff = (ks * 16 + kq * 4) ^ swz;        // dwords
            #pragma unroll
            for (int mt = 0; mt < 4; ++mt) {
                int idx = ((mt * 16 + li) * 64 + ch * 32 + aoff) * 2;
                bf16x8 ah = *(const bf16x8*)&smem[idx];
                #pragma unroll
                for (int nt = 0; nt < 2; ++nt) {
                    int i = ch * 4 + ks * 2 + nt;
                    acc[mt][nt] = __builtin_amdgcn_mfma_f32_16x16x32_bf16(ah, w2hr[i], acc[mt][nt], 0, 0, 0);
                    acc[mt][nt] = __builtin_amdgcn_mfma_f32_16x16x32_bf16(ah, w2lr[i], acc[mt][nt], 0, 0, 0);
                }
            }
        }
    }

    // ---- epilogue: bias+relu; z2 -> LDS (row-major); BN stats; pool sums ----
    float bb0 = b2[n0 + li], bb1 = b2[n0 + 16 + li];
    int btr[4][4];
    #pragma unroll
    for (int mt = 0; mt < 4; ++mt)
        #pragma unroll
        for (int reg = 0; reg < 4; ++reg) {
            int grow = row0 + mt * 16 + kq * 4 + reg;
            btr[mt][reg] = (grow < N) ? batch[grow] : -1;
        }
    __syncthreads();                    // all GEMM2 z1-reads done before overwrite
    float s0 = 0.f, q0 = 0.f, s1 = 0.f, q1 = 0.f;
    #pragma unroll
    for (int mt = 0; mt < 4; ++mt) {
        #pragma unroll
        for (int reg = 0; reg < 4; ++reg) {
            int r = mt * 16 + kq * 4 + reg;
            float v0 = fmaxf(acc[mt][0][reg] + bb0, 0.f);
            float v1 = fmaxf(acc[mt][1][reg] + bb1, 0.f);
            smem[r * 128 + n0 + li]      = f2bf(v0);
            smem[r * 128 + n0 + 16 + li] = f2bf(v1);
            if (btr[mt][reg] >= 0) {
                s0 += v0; q0 += v0 * v0; s1 += v1; q1 += v1 * v1;
            }
        }
    }
    __syncthreads();
    // coalesced store: 64 rows x 16 uint4 (full 64B lines)
    {
        int valid = N - row0; if (valid > 64) valid = 64;
        int tot = valid * 16;
        for (int i = t; i < tot; i += 256) {
            int r = i >> 4, c = i & 15;
            ((uint4*)&Hout[(size_t)(row0 + r) * HID])[c] = ((const uint4*)smem)[r * 16 + c];
        }
    }
    s0 += __shfl_xor(s0, 16); s0 += __shfl_xor(s0, 32);
    q0 += __shfl_xor(q0, 16); q0 += __shfl_xor(q0, 32);
    s1 += __shfl_xor(s1, 16); s1 += __shfl_xor(s1, 32);
    q1 += __shfl_xor(q1, 16); q1 += __shfl_xor(q1, 32);
    if (kq == 0) {
        float* ss = stat_sl + (blockIdx.x & 7) * 768;   // slice: sum[0..127] | sq[128..255]
        unsafeAtomicAdd(&ss[n0 + li], s0);
        unsafeAtomicAdd(&ss[128 + n0 + li], q0);
        unsafeAtomicAdd(&ss[n0 + 16 + li], s1);
        unsafeAtomicAdd(&ss[128 + n0 + 16 + li], q1);
    }
    // per-graph raw sums (affine applied later in k_mlp)
    int lastr = N - 1; if (lastr > row0 + 63) lastr = row0 + 63;
    int g_lo = batch[row0], g_hi = batch[lastr];
    int loff = layer * HID;
    for (int g = g_lo; g <= g_hi; ++g) {
        float p0 = 0.f, p1 = 0.f;
        #pragma unroll
        for (int mt = 0; mt < 4; ++mt)
            #pragma unroll
            for (int reg = 0; reg < 4; ++reg) {
                if (btr[mt][reg] == g) {
                    p0 += fmaxf(acc[mt][0][reg] + bb0, 0.f);
                    p1 += fmaxf(acc[mt][1][reg] + bb1, 0.f);
                }
            }
        p0 += __shfl_xor(p0, 16); p0 += __shfl_xor(p0, 32);
        p1 += __shfl_xor(p1, 16); p1 += __shfl_xor(p1, 32);
        if (kq == 0) {
            unsafeAtomicAdd(&gsum[(size_t)g * 384 + loff + n0 + li], p0);
            unsafeAtomicAdd(&gsum[(size_t)g * 384 + loff + n0 + 16 + li], p1);
        }
    }
}

// ---------------------------------------------------------------------------
// final MLP: 8 graphs/block, w1 value loaded once per k used 8x; BN stats
// folded inline from the 8 slices (k_sfold eliminated).
// ---------------------------------------------------------------------------
__global__ __launch_bounds__(128) void k_mlp(const int* __restrict__ batch, int N,
                     const float* __restrict__ gsum, const float* __restrict__ sliced,
                     const float* __restrict__ gamma, const float* __restrict__ beta,
                     const float* __restrict__ w1, const float* __restrict__ b1,
                     const float* __restrict__ w2, const float* __restrict__ b2,
                     float* __restrict__ out) {
    __shared__ float gl[8][384];
    __shared__ float hh[8][128];
    int g0 = blockIdx.x * 8, t = threadIdx.x;   // 128 threads, 8 graphs
    float invn = 1.0f / (float)N;
    // BN affine per feature (same for all graphs) — fold 8 slices inline
    float sc[NLAYERS], sh[NLAYERS];
    #pragma unroll
    for (int l = 0; l < NLAYERS; ++l) {
        float sum_ = 0.f, sq_ = 0.f;
        #pragma unroll
        for (int k = 0; k < 8; ++k) {
            sum_ += sliced[k * 768 + l * 256 + t];
            sq_  += sliced[k * 768 + l * 256 + 128 + t];
        }
        float mu = sum_ * invn;
        float var = sq_ * invn - mu * mu;
        float inv = rsqrtf(var + BN_EPS);
        sc[l] = gamma[l * HID + t] * inv;
        sh[l] = beta[l * HID + t] - mu * sc[l];
    }
    for (int j = 0; j < 8; ++j) {
        int g = g0 + j;
        int start, end;
        { int lo = 0, hi = N; while (lo < hi) { int m = (lo + hi) >> 1; if (batch[m] < g) lo = m + 1; else hi = m; } start = lo; }
        { int lo = start, hi = N; while (lo < hi) { int m = (lo + hi) >> 1; if (batch[m] < g + 1) lo = m + 1; else hi = m; } end = lo; }
        float cnt = (float)(end - start);
        float invc = 1.0f / fmaxf(cnt, 1.0f);
        #pragma unroll
        for (int l = 0; l < NLAYERS; ++l)
            gl[j][l * 128 + t] = (gsum[(size_t)g * 384 + l * 128 + t] * sc[l] + sh[l] * cnt) * invc;
    }
    __syncthreads();
    float acc[8];
    #pragma unroll
    for (int j = 0; j < 8; ++j) acc[j] = b1[t];
    for (int k = 0; k < 384; ++k) {
        float wv = w1[k * HID + t];
        #pragma unroll
        for (int j = 0; j < 8; ++j) acc[j] = fmaf(gl[j][k], wv, acc[j]);
    }
    #pragma unroll
    for (int j = 0; j < 8; ++j) hh[j][t] = fmaxf(acc[j], 0.f);
    __syncthreads();
    if (t < 80) {
        int j = t / 10, o = t % 10;
        float a2 = b2[o];
        for (int k = 0; k < 128; ++k) a2 = fmaf(hh[j][k], w2[k * 10 + o], a2);
        out[(g0 + j) * 10 + o] = a2;
    }
}

// ---------------------------------------------------------------------------
extern "C" void kernel_launch(void* const* d_in, const int* in_sizes, int n_in,
                              void* d_out, int out_size, void* d_ws, size_t ws_size,
                              hipStream_t stream) {
    const float* x     = (const float*)d_in[0];
    const int*   ei    = (const int*)d_in[1];
    const int*   batch = (const int*)d_in[2];
    const float* W1    = (const float*)d_in[3];
    const float* b1    = (const float*)d_in[4];
    const float* W2    = (const float*)d_in[5];
    const float* b2    = (const float*)d_in[6];
    const float* gamma = (const float*)d_in[7];
    const float* beta  = (const float*)d_in[8];
    const float* epsg  = (const float*)d_in[9];
    const float* l1w   = (const float*)d_in[10];
    const float* l1b   = (const float*)d_in[11];
    const float* l2w   = (const float*)d_in[12];
    const float* l2b   = (const float*)d_in[13];

    const int N = in_sizes[0] / HID;
    const int E = in_sizes[1] / 2;
    const int* src = ei;
    const int* dst = ei + E;
    const int nb = (N + NPB - 1) / NPB;           // <= 512
    const int eblk = (E + EB - 1) / EB;           // <= 512

    float* w = (float*)d_ws;
    const size_t NF = (size_t)N * HID;
    ushort* xb    = (ushort*)(w + NF);                       // x as bf16 (NF ushorts)
    ushort* hb[3] = { xb + NF, xb + 2 * NF, xb + 3 * NF };   // layer outputs, bf16
    ushort* z0buf = xb + 4 * NF;                             // aggregated input (NF ushorts)
    float* sliced = w + 4 * NF;       // 8 slices x 3 layers x 256 = 6144
    float* gsum   = sliced + 6144;    // 512 * 384 = 196608
    int*   btot   = (int*)(gsum + (size_t)NGRAPH * 384);     // 513
    int*   rowptr = btot + 513;                              // N + 1
    int*   csr    = rowptr + N + 1;                          // E
    int*   bbase  = csr + E;                                 // nb + 2
    ushort* wt  = (ushort*)(((uintptr_t)(bbase + nb + 2) + 15) & ~(uintptr_t)15);
    ushort* w1h = wt;
    ushort* w1l = wt + 49152;
    ushort* w2h = wt + 98304;
    ushort* w2l = wt + 147456;

    unsigned* pairs  = (unsigned*)w;                // E uints (CSR build only)
    int*      blkcnt = (int*)(w + 2 * 1024 * 1024); // eblk*512 (CSR build only)

    // zero sliced + gsum + btot in one stream-ordered memset
    hipMemsetAsync(sliced, 0, (6144 + (size_t)NGRAPH * 384 + 513) * sizeof(float), stream);

    const int total4 = (int)(NF / 4);
    const int xblocks = (total4 + 255) / 256;
    const int prep_blocks = 384 + xblocks + eblk;
    k_prep<<<prep_blocks, 256, 0, stream>>>((const float4*)x, xb, total4,
                                            W1, w1h, w1l, W2, w2h, w2l, NLAYERS * HID * HID,
                                            xblocks, dst, E, blkcnt, btot);

    // ---- build CSR ----
    k_bscan<<<1, 512, 0, stream>>>(btot, nb, E, bbase, rowptr + N);
    k_colscan<<<nb, 512, 0, stream>>>(blkcnt, eblk, bbase);
    k_bscatter<<<eblk, 256, 0, stream>>>(src, dst, E, blkcnt, pairs);
    k_bbuild<<<nb, 256, 0, stream>>>(pairs, bbase, N, rowptr, csr);

    for (int l = 0; l < NLAYERS; ++l) {
        const ushort* hin = (l == 0) ? xb : hb[l - 1];
        const float* psl    = (l == 0) ? nullptr : (sliced + (l - 1) * 256);
        const float* grow_  = gamma + (l == 0 ? 0 : (l - 1)) * HID;
        const float* brow_  = beta  + (l == 0 ? 0 : (l - 1)) * HID;

        k_agg<<<(N + 15) / 16, 256, 0, stream>>>(
            rowptr, csr, (const uint2*)hin, psl, grow_, brow_, epsg, l, z0buf, N);

        k_mlp_dense<<<(N + 63) / 64, 256, 0, stream>>>(
            (const uint4*)z0buf, l, batch,
            w1h + (size_t)l * 16384, w1l + (size_t)l * 16384, b1 + l * HID,
            w2h + (size_t)l * 16384, w2l + (size_t)l * 16384, b2 + l * HID,
            hb[l], sliced + l * 256, gsum, N);
    }

    k_mlp<<<NGRAPH / 8, 128, 0, stream>>>(batch, N, gsum, sliced, gamma, beta,
                                          l1w, l1b, l2w, l2b, (float*)d_out);
}

// Round 12
// 517.646 us; speedup vs baseline: 1.1634x; 1.0862x over previous
//
#include <hip/hip_runtime.h>

#define HID 128
#define NGRAPH 512
#define NLAYERS 3
#define BN_EPS 1e-5f
#define NPB 256          // nodes per bucket (CSR build)
#define EB 4096          // edges per build block

typedef __attribute__((ext_vector_type(8))) short bf16x8;
typedef __attribute__((ext_vector_type(4))) float f32x4;
typedef __attribute__((ext_vector_type(2))) float f32x2;

__device__ inline unsigned short f2bf(float x) {
    union { float f; unsigned u; } v; v.f = x;
    unsigned r = v.u + 0x7FFFu + ((v.u >> 16) & 1u);
    return (unsigned short)(r >> 16);
}
__device__ inline float bf2f(unsigned short b) {
    union { float f; unsigned u; } v; v.u = ((unsigned)b) << 16; return v.f;
}
// 1 dword (2 packed bf16) -> f32x2 {lo, hi}
__device__ inline f32x2 bfp(unsigned u) {
    union { unsigned q; float f; } lo, hi;
    lo.q = u << 16; hi.q = u & 0xFFFF0000u;
    f32x2 r; r[0] = lo.f; r[1] = hi.f; return r;
}

// ---------------------------------------------------------------------------
// prep (one launch): W split+transpose | x->bf16 | ecount (+btot atomics)
// | graph-count histogram.  Zeroing of sliced/gsum/btot/gcnt via memset.
// ---------------------------------------------------------------------------
__global__ void k_prep(const float4* __restrict__ x4, ushort* __restrict__ xb, int total4,
                       const float* __restrict__ W1, ushort* __restrict__ w1h, ushort* __restrict__ w1l,
                       const float* __restrict__ W2, ushort* __restrict__ w2h, ushort* __restrict__ w2l,
                       int wtotal, int xblocks,
                       const int* __restrict__ dst, int E, int* __restrict__ blkcnt,
                       int* __restrict__ btot,
                       const int* __restrict__ batch, int N, int eblk, int* __restrict__ gcnt) {
    __shared__ int hist[512];
    int b = blockIdx.x, t = threadIdx.x;
    if (b < 384) {
        int gid = b * 256 + t;
        const float* W; ushort *Wh, *Wl; int e;
        if (gid < wtotal) { W = W1; Wh = w1h; Wl = w1l; e = gid; }
        else              { W = W2; Wh = w2h; Wl = w2l; e = gid - wtotal; }
        if (e < wtotal) {
            int l = e >> 14, rem = e & 16383, k = rem >> 7, n = rem & 127;
            float v = W[e];
            ushort hi = f2bf(v);
            ushort lo = f2bf(v - bf2f(hi));
            int o = (l << 14) + (n << 7) + k;
            Wh[o] = hi; Wl[o] = lo;
        }
    } else if (b < 384 + xblocks) {
        int i = (b - 384) * 256 + t;
        if (i < total4) {
            float4 v = x4[i];
            uint2 p;
            p.x = ((unsigned)f2bf(v.y) << 16) | f2bf(v.x);
            p.y = ((unsigned)f2bf(v.w) << 16) | f2bf(v.z);
            ((uint2*)xb)[i] = p;
        }
    } else if (b < 384 + xblocks + eblk) {
        // edge count histogram + bucket-total atomics (int, order-independent)
        int b2 = b - (384 + xblocks);
        hist[t] = 0; hist[t + 256] = 0;
        __syncthreads();
        int base = b2 * EB;
        #pragma unroll
        for (int i = 0; i < 16; ++i) {
            int e = base + i * 256 + t;
            if (e < E) atomicAdd(&hist[dst[e] >> 8], 1);
        }
        __syncthreads();
        blkcnt[b2 * 512 + t]       = hist[t];
        blkcnt[b2 * 512 + t + 256] = hist[t + 256];
        if (hist[t])       atomicAdd(&btot[t], hist[t]);
        if (hist[t + 256]) atomicAdd(&btot[t + 256], hist[t + 256]);
    } else {
        // per-graph node count histogram (4096 nodes per block)
        int b3 = b - (384 + xblocks + eblk);
        hist[t] = 0; hist[t + 256] = 0;
        __syncthreads();
        int base = b3 * 4096;
        #pragma unroll
        for (int i = 0; i < 16; ++i) {
            int n = base + i * 256 + t;
            if (n < N) atomicAdd(&hist[batch[n]], 1);
        }
        __syncthreads();
        if (hist[t])       atomicAdd(&gcnt[t], hist[t]);
        if (hist[t + 256]) atomicAdd(&gcnt[t + 256], hist[t + 256]);
    }
}

// ---------------------------------------------------------------------------
// CSR build, deterministic two-level
// ---------------------------------------------------------------------------
__global__ __launch_bounds__(512) void k_bscan(const int* __restrict__ tot, int nb, int E,
                                               int* __restrict__ bbase, int* __restrict__ rowptrN) {
    __shared__ int sh[512];
    int t = threadIdx.x;                       // 512 threads
    sh[t] = (t < nb) ? tot[t] : 0;
    __syncthreads();
    #pragma unroll
    for (int s = 1; s < 512; s <<= 1) {
        int v = (t >= s) ? sh[t - s] : 0;
        __syncthreads();
        sh[t] += v;
        __syncthreads();
    }
    if (t < nb) bbase[t] = (t == 0) ? 0 : sh[t - 1];   // exclusive
    if (t == 0) { bbase[nb] = E; *rowptrN = E; }
}

// per-column exclusive scan of blkcnt (bucket b), parallel Hillis-Steele.
__global__ __launch_bounds__(512) void k_colscan(int* __restrict__ blkcnt, int eblk,
                                                 const int* __restrict__ bbase) {
    __shared__ int sh[512];
    int t = threadIdx.x;
    int b = blockIdx.x;
    sh[t] = (t < eblk) ? blkcnt[t * 512 + b] : 0;
    __syncthreads();
    #pragma unroll
    for (int s = 1; s < 512; s <<= 1) {
        int v = (t >= s) ? sh[t - s] : 0;
        __syncthreads();
        sh[t] += v;
        __syncthreads();
    }
    int excl = (t == 0) ? 0 : sh[t - 1];
    if (t < eblk) blkcnt[t * 512 + b] = bbase[b] + excl;
}

__global__ __launch_bounds__(256) void k_bscatter(const int* __restrict__ src,
                                                  const int* __restrict__ dst, int E,
                                                  const int* __restrict__ blkcnt,
                                                  unsigned* __restrict__ pairs) {
    __shared__ int hist[512];    // local cursor (starts at 0)
    __shared__ int lbase[512];   // absolute base for this block's chunk per bucket
    int t = threadIdx.x;
    hist[t] = 0; hist[t + 256] = 0;
    lbase[t]       = blkcnt[blockIdx.x * 512 + t];
    lbase[t + 256] = blkcnt[blockIdx.x * 512 + t + 256];
    __syncthreads();
    int base = blockIdx.x * EB;
    #pragma unroll
    for (int i = 0; i < 16; ++i) {
        int e = base + i * 256 + t;
        if (e < E) {
            int d = dst[e];
            int b = d >> 8;
            int pos = lbase[b] + atomicAdd(&hist[b], 1);
            pairs[pos] = ((unsigned)(d & 255) << 24) | (unsigned)src[e];
        }
    }
}

__global__ __launch_bounds__(256) void k_bbuild(const unsigned* __restrict__ pairs,
                                                const int* __restrict__ bbase, int N,
                                                int* __restrict__ rowptr, int* __restrict__ csr) {
    __shared__ int cnt[256];
    __shared__ int off[256];
    int t = threadIdx.x;
    int b = blockIdx.x;
    int base = bbase[b], bcount = bbase[b + 1] - base;
    cnt[t] = 0;
    __syncthreads();
    for (int i = t; i < bcount; i += 256) atomicAdd(&cnt[pairs[base + i] >> 24], 1);
    __syncthreads();
    off[t] = cnt[t];
    __syncthreads();
    for (int s = 1; s < 256; s <<= 1) {
        int v = (t >= s) ? off[t - s] : 0;
        __syncthreads();
        off[t] += v;
        __syncthreads();
    }
    int excl = (t == 0) ? 0 : off[t - 1];
    int node = b * NPB + t;
    if (node < N) rowptr[node] = base + excl;
    cnt[t] = excl;                      // becomes per-node cursor
    __syncthreads();
    for (int i = t; i < bcount; i += 256) {
        unsigned p = pairs[base + i];
        int dl = p >> 24;
        int pos = base + atomicAdd(&cnt[dl], 1);
        csr[pos] = (int)(p & 0xFFFFFFu);
    }
}

// ---------------------------------------------------------------------------
// part 1: pure gather+BN -> z0.  (R9/R11 known-good config: (256,6), 40 VGPR,
// no spill.  R10's (256,8) spilled — do not raise.)
// ---------------------------------------------------------------------------
__global__ __launch_bounds__(256, 6) void k_agg(
        const int* __restrict__ rowptr, const int* __restrict__ csr_src,
        const uint2* __restrict__ hinb,
        const float* __restrict__ prev_sliced,     // null for layer 0; else 8 slices (stride 768)
        const float* __restrict__ g_row, const float* __restrict__ be_row,
        const float* __restrict__ eps_gin, int layer,
        ushort* __restrict__ z0out, int N) {
    __shared__ float sfold[256];
    const int t = threadIdx.x;
    const int lane = t & 63;
    const int wv = t >> 6;
    const int q = lane >> 4;           // 0..3: row within the wave
    const int f = lane & 15;           // uint4 lane (8 bf16 features) within row

    if (prev_sliced) {
        float s = 0.f;
        #pragma unroll
        for (int k = 0; k < 8; ++k) s += prev_sliced[k * 768 + t];
        sfold[t] = s;                  // sum[0..127] | sq[128..255]
        __syncthreads();
    }

    f32x2 scv2[4], shv2[4];
    if (prev_sliced) {
        float invn = 1.0f / (float)N;
        #pragma unroll
        for (int d = 0; d < 4; ++d) {
            #pragma unroll
            for (int h = 0; h < 2; ++h) {
                int fi = f * 8 + d * 2 + h;
                float mu = sfold[fi] * invn;
                float var = sfold[128 + fi] * invn - mu * mu;
                float inv = rsqrtf(var + BN_EPS);
                float scj = g_row[fi] * inv;
                scv2[d][h] = scj; shv2[d][h] = be_row[fi] - mu * scj;
            }
        }
    } else {
        #pragma unroll
        for (int d = 0; d < 4; ++d) { scv2[d] = (f32x2){1.f, 1.f}; shv2[d] = (f32x2){0.f, 0.f}; }
    }
    float e1 = 1.0f + eps_gin[layer];
    const uint4* hin4 = (const uint4*)hinb;

    int r = blockIdx.x * 16 + wv * 4 + q;     // global row
    f32x2 a2[4];
    #pragma unroll
    for (int d = 0; d < 4; ++d) a2[d] = (f32x2){0.f, 0.f};
    float cdeg = 0.f;
    if (r < N) {
        int beg = rowptr[r], end = rowptr[r + 1];
        uint4 hv = hin4[(size_t)r * 16 + f];
        a2[0] = e1 * bfp(hv.x); a2[1] = e1 * bfp(hv.y);
        a2[2] = e1 * bfp(hv.z); a2[3] = e1 * bfp(hv.w);
        int p = beg;
        // ---- full batches: NO masks ----
        for (; p + 8 <= end; p += 8) {
            int s0 = csr_src[p],     s1 = csr_src[p + 1], s2 = csr_src[p + 2], s3 = csr_src[p + 3];
            int s4 = csr_src[p + 4], s5 = csr_src[p + 5], s6 = csr_src[p + 6], s7 = csr_src[p + 7];
            uint4 v0 = hin4[(size_t)s0 * 16 + f];
            uint4 v1 = hin4[(size_t)s1 * 16 + f];
            uint4 v2 = hin4[(size_t)s2 * 16 + f];
            uint4 v3 = hin4[(size_t)s3 * 16 + f];
            uint4 v4 = hin4[(size_t)s4 * 16 + f];
            uint4 v5 = hin4[(size_t)s5 * 16 + f];
            uint4 v6 = hin4[(size_t)s6 * 16 + f];
            uint4 v7 = hin4[(size_t)s7 * 16 + f];
            a2[0] += ((bfp(v0.x) + bfp(v1.x)) + (bfp(v2.x) + bfp(v3.x)))
                   + ((bfp(v4.x) + bfp(v5.x)) + (bfp(v6.x) + bfp(v7.x)));
            a2[1] += ((bfp(v0.y) + bfp(v1.y)) + (bfp(v2.y) + bfp(v3.y)))
                   + ((bfp(v4.y) + bfp(v5.y)) + (bfp(v6.y) + bfp(v7.y)));
            a2[2] += ((bfp(v0.z) + bfp(v1.z)) + (bfp(v2.z) + bfp(v3.z)))
                   + ((bfp(v4.z) + bfp(v5.z)) + (bfp(v6.z) + bfp(v7.z)));
            a2[3] += ((bfp(v0.w) + bfp(v1.w)) + (bfp(v2.w) + bfp(v3.w)))
                   + ((bfp(v4.w) + bfp(v5.w)) + (bfp(v6.w) + bfp(v7.w)));
        }
        // ---- single partial tail: clamp + dword-level masks ----
        if (p < end) {
            int last = end - 1;
            int c1 = min(p + 1, last), c2 = min(p + 2, last), c3 = min(p + 3, last);
            int c4 = min(p + 4, last), c5 = min(p + 5, last), c6 = min(p + 6, last);
            int s0 = csr_src[p],  s1 = csr_src[c1], s2 = csr_src[c2], s3 = csr_src[c3];
            int s4 = csr_src[c4], s5 = csr_src[c5], s6 = csr_src[c6];
            uint4 v0 = hin4[(size_t)s0 * 16 + f];
            uint4 v1 = hin4[(size_t)s1 * 16 + f];
            uint4 v2 = hin4[(size_t)s2 * 16 + f];
            uint4 v3 = hin4[(size_t)s3 * 16 + f];
            uint4 v4 = hin4[(size_t)s4 * 16 + f];
            uint4 v5 = hin4[(size_t)s5 * 16 + f];
            uint4 v6 = hin4[(size_t)s6 * 16 + f];
            int rem = end - p;           // 1..7
            unsigned m1 = (rem > 1) ? 0xFFFFFFFFu : 0u;
            unsigned m2 = (rem > 2) ? 0xFFFFFFFFu : 0u;
            unsigned m3 = (rem > 3) ? 0xFFFFFFFFu : 0u;
            unsigned m4 = (rem > 4) ? 0xFFFFFFFFu : 0u;
            unsigned m5 = (rem > 5) ? 0xFFFFFFFFu : 0u;
            unsigned m6 = (rem > 6) ? 0xFFFFFFFFu : 0u;
            a2[0] += ((bfp(v0.x) + bfp(v1.x & m1)) + (bfp(v2.x & m2) + bfp(v3.x & m3)))
                   + ((bfp(v4.x & m4) + bfp(v5.x & m5)) + bfp(v6.x & m6));
            a2[1] += ((bfp(v0.y) + bfp(v1.y & m1)) + (bfp(v2.y & m2) + bfp(v3.y & m3)))
                   + ((bfp(v4.y & m4) + bfp(v5.y & m5)) + bfp(v6.y & m6));
            a2[2] += ((bfp(v0.z) + bfp(v1.z & m1)) + (bfp(v2.z & m2) + bfp(v3.z & m3)))
                   + ((bfp(v4.z & m4) + bfp(v5.z & m5)) + bfp(v6.z & m6));
            a2[3] += ((bfp(v0.w) + bfp(v1.w & m1)) + (bfp(v2.w & m2) + bfp(v3.w & m3)))
                   + ((bfp(v4.w & m4) + bfp(v5.w & m5)) + bfp(v6.w & m6));
        }
        cdeg = e1 + (float)(end - beg);
    }
    f32x2 rr2[4];
    #pragma unroll
    for (int d = 0; d < 4; ++d) rr2[d] = scv2[d] * a2[d] + cdeg * shv2[d];
    uint4 ph;
    ph.x = ((unsigned)f2bf(rr2[0][1]) << 16) | f2bf(rr2[0][0]);
    ph.y = ((unsigned)f2bf(rr2[1][1]) << 16) | f2bf(rr2[1][0]);
    ph.z = ((unsigned)f2bf(rr2[2][1]) << 16) | f2bf(rr2[2][0]);
    ph.w = ((unsigned)f2bf(rr2[3][1]) << 16) | f2bf(rr2[3][0]);
    if (r < N) ((uint4*)z0out)[(size_t)r * 16 + f] = ph;
}

// ---------------------------------------------------------------------------
// part 2: dense MLP over z0 (64 rows/block) — weights hoisted into registers
// once per block, launch_bounds(256,2).  BN-stat atomics 8-way sliced.
// ---------------------------------------------------------------------------
__global__ __launch_bounds__(256, 2) void k_mlp_dense(
        const uint4* __restrict__ z0, int layer, const int* __restrict__ batch,
        const ushort* __restrict__ w1h, const ushort* __restrict__ w1l,
        const float* __restrict__ b1,
        const ushort* __restrict__ w2h, const ushort* __restrict__ w2l,
        const float* __restrict__ b2,
        ushort* __restrict__ Hout, float* __restrict__ stat_sl,
        float* __restrict__ gsum, int N) {
    __shared__ __align__(16) ushort smem[8192];    // 16 KB
    const int t = threadIdx.x;
    const int lane = t & 63;
    const int wv = t >> 6;
    const int li = lane & 15;
    const int kq = lane >> 4;
    const int n0 = wv * 32;
    const int row0 = blockIdx.x * 64;
    const int swz = (li & 7) * 4;

    // ---- hoist all weight fragments into registers (32 x 16B loads) ----
    bf16x8 w1hr[8], w1lr[8], w2hr[8], w2lr[8];
    #pragma unroll
    for (int ch = 0; ch < 2; ++ch)
        #pragma unroll
        for (int ks = 0; ks < 2; ++ks)
            #pragma unroll
            for (int nt = 0; nt < 2; ++nt) {
                int i = ch * 4 + ks * 2 + nt;
                size_t wo = (size_t)(n0 + nt * 16 + li) * 128 + (ch * 64 + ks * 32 + kq * 8);
                w1hr[i] = *(const bf16x8*)&w1h[wo];
                w1lr[i] = *(const bf16x8*)&w1l[wo];
                w2hr[i] = *(const bf16x8*)&w2h[wo];
                w2lr[i] = *(const bf16x8*)&w2l[wo];
            }

    // ---- stage z0 tile -> LDS (swizzled), zero-fill rows >= N ----
    {
        const uint4 zz = {0u, 0u, 0u, 0u};
        #pragma unroll
        for (int i = 0; i < 4; ++i) {
            int idx = i * 256 + t;             // 0..1023
            int r = idx >> 4, f = idx & 15;
            uint4 v = (row0 + r < N) ? z0[(size_t)(row0 + r) * 16 + f] : zz;
            ((uint4*)smem)[r * 16 + (f ^ (r & 7))] = v;
        }
    }
    __syncthreads();

    f32x4 acc[4][2];
    #pragma unroll
    for (int i = 0; i < 4; ++i) {
        acc[i][0] = (f32x4){0.f, 0.f, 0.f, 0.f};
        acc[i][1] = (f32x4){0.f, 0.f, 0.f, 0.f};
    }

    // ---------------- GEMM1: z1 = z0 @ W1 (registers only for W) ----------------
    #pragma unroll
    for (int ch = 0; ch < 2; ++ch) {
        #pragma unroll
        for (int ks = 0; ks < 2; ++ks) {
            int kcol = ch * 8 + ks * 4 + kq;            // u4 col 0..15
            #pragma unroll
            for (int mt = 0; mt < 4; ++mt) {
                int r = mt * 16 + li;
                int hw = (r * 16 + (kcol ^ (li & 7))) * 8;
                bf16x8 ah = *(const bf16x8*)&smem[hw];
                #pragma unroll
                for (int nt = 0; nt < 2; ++nt) {
                    int i = ch * 4 + ks * 2 + nt;
                    acc[mt][nt] = __builtin_amdgcn_mfma_f32_16x16x32_bf16(ah, w1hr[i], acc[mt][nt], 0, 0, 0);
                    acc[mt][nt] = __builtin_amdgcn_mfma_f32_16x16x32_bf16(ah, w1lr[i], acc[mt][nt], 0, 0, 0);
                }
            }
        }
    }

    // ---- z1 = relu(acc + b1) -> Z overlay (A-layout, bf16, swizzled) ----
    float bz0 = b1[n0 + li], bz1 = b1[n0 + 16 + li];
    __syncthreads();                    // all GEMM1 A-reads done before overwrite
    #pragma unroll
    for (int mt = 0; mt < 4; ++mt) {
        #pragma unroll
        for (int nt = 0; nt < 2; ++nt) {
            int c = n0 + nt * 16 + li;
            int dk = c >> 1;
            int halfbase = (dk >> 5) * 32;
            int dlow = dk & 31;
            int codd = c & 1;
            float bias = nt ? bz1 : bz0;
            #pragma unroll
            for (int reg = 0; reg < 4; ++reg) {
                int r = mt * 16 + kq * 4 + reg;
                float v = fmaxf(acc[mt][nt][reg] + bias, 0.f);
                int us = (r * 64 + halfbase + (dlow ^ ((r & 7) * 4))) * 2 + codd;
                smem[us] = f2bf(v);
            }
        }
    }
    #pragma unroll
    for (int i = 0; i < 4; ++i) {
        acc[i][0] = (f32x4){0.f, 0.f, 0.f, 0.f};
        acc[i][1] = (f32x4){0.f, 0.f, 0.f, 0.f};
    }
    __syncthreads();

    // ---------------- GEMM2: z2 = z1 @ W2 (registers only for W) ----------------
    #pragma unroll
    for (int ch = 0; ch < 2; ++ch) {
        #pragma unroll
        for (int ks = 0; ks < 2; ++ks) {
            int aoff = (ks * 16 + kq * 4) ^ swz;        // dwords
            #pragma unroll
            for (int mt = 0; mt < 4; ++mt) {
                int idx = ((mt * 16 + li) * 64 + ch * 32 + aoff) * 2;
                bf16x8 ah = *(const bf16x8*)&smem[idx];
                #pragma unroll
                for (int nt = 0; nt < 2; ++nt) {
                    int i = ch * 4 + ks * 2 + nt;
                    acc[mt][nt] = __builtin_amdgcn_mfma_f32_16x16x32_bf16(ah, w2hr[i], acc[mt][nt], 0, 0, 0);
                    acc[mt][nt] = __builtin_amdgcn_mfma_f32_16x16x32_bf16(ah, w2lr[i], acc[mt][nt], 0, 0, 0);
                }
            }
        }
    }

    // ---- epilogue: bias+relu; z2 -> LDS (row-major); BN stats; pool sums ----
    float bb0 = b2[n0 + li], bb1 = b2[n0 + 16 + li];
    int btr[4][4];
    #pragma unroll
    for (int mt = 0; mt < 4; ++mt)
        #pragma unroll
        for (int reg = 0; reg < 4; ++reg) {
            int grow = row0 + mt * 16 + kq * 4 + reg;
            btr[mt][reg] = (grow < N) ? batch[grow] : -1;
        }
    __syncthreads();                    // all GEMM2 z1-reads done before overwrite
    float s0 = 0.f, q0 = 0.f, s1 = 0.f, q1 = 0.f;
    #pragma unroll
    for (int mt = 0; mt < 4; ++mt) {
        #pragma unroll
        for (int reg = 0; reg < 4; ++reg) {
            int r = mt * 16 + kq * 4 + reg;
            float v0 = fmaxf(acc[mt][0][reg] + bb0, 0.f);
            float v1 = fmaxf(acc[mt][1][reg] + bb1, 0.f);
            smem[r * 128 + n0 + li]      = f2bf(v0);
            smem[r * 128 + n0 + 16 + li] = f2bf(v1);
            if (btr[mt][reg] >= 0) {
                s0 += v0; q0 += v0 * v0; s1 += v1; q1 += v1 * v1;
            }
        }
    }
    __syncthreads();
    // coalesced store: 64 rows x 16 uint4 (full 64B lines)
    {
        int valid = N - row0; if (valid > 64) valid = 64;
        int tot = valid * 16;
        for (int i = t; i < tot; i += 256) {
            int r = i >> 4, c = i & 15;
            ((uint4*)&Hout[(size_t)(row0 + r) * HID])[c] = ((const uint4*)smem)[r * 16 + c];
        }
    }
    s0 += __shfl_xor(s0, 16); s0 += __shfl_xor(s0, 32);
    q0 += __shfl_xor(q0, 16); q0 += __shfl_xor(q0, 32);
    s1 += __shfl_xor(s1, 16); s1 += __shfl_xor(s1, 32);
    q1 += __shfl_xor(q1, 16); q1 += __shfl_xor(q1, 32);
    if (kq == 0) {
        float* ss = stat_sl + (blockIdx.x & 7) * 768;   // slice: sum[0..127] | sq[128..255]
        unsafeAtomicAdd(&ss[n0 + li], s0);
        unsafeAtomicAdd(&ss[128 + n0 + li], q0);
        unsafeAtomicAdd(&ss[n0 + 16 + li], s1);
        unsafeAtomicAdd(&ss[128 + n0 + 16 + li], q1);
    }
    // per-graph raw sums (affine applied later in k_mlp)
    int lastr = N - 1; if (lastr > row0 + 63) lastr = row0 + 63;
    int g_lo = batch[row0], g_hi = batch[lastr];
    int loff = layer * HID;
    for (int g = g_lo; g <= g_hi; ++g) {
        float p0 = 0.f, p1 = 0.f;
        #pragma unroll
        for (int mt = 0; mt < 4; ++mt)
            #pragma unroll
            for (int reg = 0; reg < 4; ++reg) {
                if (btr[mt][reg] == g) {
                    p0 += fmaxf(acc[mt][0][reg] + bb0, 0.f);
                    p1 += fmaxf(acc[mt][1][reg] + bb1, 0.f);
                }
            }
        p0 += __shfl_xor(p0, 16); p0 += __shfl_xor(p0, 32);
        p1 += __shfl_xor(p1, 16); p1 += __shfl_xor(p1, 32);
        if (kq == 0) {
            unsafeAtomicAdd(&gsum[(size_t)g * 384 + loff + n0 + li], p0);
            unsafeAtomicAdd(&gsum[(size_t)g * 384 + loff + n0 + 16 + li], p1);
        }
    }
}

// ---------------------------------------------------------------------------
// final MLP — R12 redesign: 512 blocks (1 graph each, 2 blocks/CU) x 256 thr.
// No binary searches (gcnt precomputed in k_prep); gl staged cooperatively
// with inline 8-slice BN fold; GEMM1 split-k across the 2 waves; head via
// wave-0 shuffle reduction.  (R11's 64-block version was 61us at 1.3% occ.)
// ---------------------------------------------------------------------------
__global__ __launch_bounds__(256) void k_mlp(const int* __restrict__ gcnt, int N,
                     const float* __restrict__ gsum, const float* __restrict__ sliced,
                     const float* __restrict__ gamma, const float* __restrict__ beta,
                     const float* __restrict__ w1, const float* __restrict__ b1,
                     const float* __restrict__ w2, const float* __restrict__ b2,
                     float* __restrict__ out) {
    __shared__ float gl[384];
    __shared__ float ph[2][128];
    __shared__ float hh[128];
    int g = blockIdx.x, t = threadIdx.x;
    float cnt = (float)gcnt[g];
    float invc = 1.0f / fmaxf(cnt, 1.0f);
    float invn = 1.0f / (float)N;
    for (int i = t; i < 384; i += 256) {
        int l = i >> 7, f = i & 127;
        float sum_ = 0.f, sq_ = 0.f;
        #pragma unroll
        for (int k = 0; k < 8; ++k) {
            sum_ += sliced[k * 768 + l * 256 + f];
            sq_  += sliced[k * 768 + l * 256 + 128 + f];
        }
        float mu = sum_ * invn;
        float var = sq_ * invn - mu * mu;
        float inv = rsqrtf(var + BN_EPS);
        float sc = gamma[l * HID + f] * inv;
        float sh = beta[l * HID + f] - mu * sc;
        gl[i] = (gsum[(size_t)g * 384 + i] * sc + sh * cnt) * invc;
    }
    __syncthreads();
    int f = t & 127, kh = t >> 7;
    float acc = kh ? 0.f : b1[f];
    for (int k = kh * 192; k < kh * 192 + 192; ++k)
        acc = fmaf(gl[k], w1[k * HID + f], acc);
    ph[kh][f] = acc;
    __syncthreads();
    if (t < 128) hh[t] = fmaxf(ph[0][t] + ph[1][t], 0.f);
    __syncthreads();
    if (t < 64) {
        float h0 = hh[t], h1 = hh[t + 64];
        float p[10];
        #pragma unroll
        for (int o = 0; o < 10; ++o)
            p[o] = h0 * w2[t * 10 + o] + h1 * w2[(t + 64) * 10 + o];
        #pragma unroll
        for (int o = 0; o < 10; ++o) {
            #pragma unroll
            for (int s = 32; s > 0; s >>= 1) p[o] += __shfl_xor(p[o], s);
        }
        if (t == 0) {
            #pragma unroll
            for (int o = 0; o < 10; ++o) out[g * 10 + o] = b2[o] + p[o];
        }
    }
}

// ---------------------------------------------------------------------------
extern "C" void kernel_launch(void* const* d_in, const int* in_sizes, int n_in,
                              void* d_out, int out_size, void* d_ws, size_t ws_size,
                              hipStream_t stream) {
    const float* x     = (const float*)d_in[0];
    const int*   ei    = (const int*)d_in[1];
    const int*   batch = (const int*)d_in[2];
    const float* W1    = (const float*)d_in[3];
    const float* b1    = (const float*)d_in[4];
    const float* W2    = (const float*)d_in[5];
    const float* b2    = (const float*)d_in[6];
    const float* gamma = (const float*)d_in[7];
    const float* beta  = (const float*)d_in[8];
    const float* epsg  = (const float*)d_in[9];
    const float* l1w   = (const float*)d_in[10];
    const float* l1b   = (const float*)d_in[11];
    const float* l2w   = (const float*)d_in[12];
    const float* l2b   = (const float*)d_in[13];

    const int N = in_sizes[0] / HID;
    const int E = in_sizes[1] / 2;
    const int* src = ei;
    const int* dst = ei + E;
    const int nb = (N + NPB - 1) / NPB;           // <= 512
    const int eblk = (E + EB - 1) / EB;           // <= 512

    float* w = (float*)d_ws;
    const size_t NF = (size_t)N * HID;
    ushort* xb    = (ushort*)(w + NF);                       // x as bf16 (NF ushorts)
    ushort* hb[3] = { xb + NF, xb + 2 * NF, xb + 3 * NF };   // layer outputs, bf16
    ushort* z0buf = xb + 4 * NF;                             // aggregated input (NF ushorts)
    float* sliced = w + 4 * NF;       // 8 slices x 3 layers x 256 = 6144
    float* gsum   = sliced + 6144;    // 512 * 384 = 196608
    int*   btot   = (int*)(gsum + (size_t)NGRAPH * 384);     // 513
    int*   gcnt   = btot + 513;                              // 512
    int*   rowptr = gcnt + 512;                              // N + 1
    int*   csr    = rowptr + N + 1;                          // E
    int*   bbase  = csr + E;                                 // nb + 2
    ushort* wt  = (ushort*)(((uintptr_t)(bbase + nb + 2) + 15) & ~(uintptr_t)15);
    ushort* w1h = wt;
    ushort* w1l = wt + 49152;
    ushort* w2h = wt + 98304;
    ushort* w2l = wt + 147456;

    unsigned* pairs  = (unsigned*)w;                // E uints (CSR build only)
    int*      blkcnt = (int*)(w + 2 * 1024 * 1024); // eblk*512 (CSR build only)

    // zero sliced + gsum + btot + gcnt in one stream-ordered memset
    hipMemsetAsync(sliced, 0, (6144 + (size_t)NGRAPH * 384 + 513 + 512) * sizeof(float), stream);

    const int total4 = (int)(NF / 4);
    const int xblocks = (total4 + 255) / 256;
    const int gblocks = (N + 4095) / 4096;
    const int prep_blocks = 384 + xblocks + eblk + gblocks;
    k_prep<<<prep_blocks, 256, 0, stream>>>((const float4*)x, xb, total4,
                                            W1, w1h, w1l, W2, w2h, w2l, NLAYERS * HID * HID,
                                            xblocks, dst, E, blkcnt, btot,
                                            batch, N, eblk, gcnt);

    // ---- build CSR ----
    k_bscan<<<1, 512, 0, stream>>>(btot, nb, E, bbase, rowptr + N);
    k_colscan<<<nb, 512, 0, stream>>>(blkcnt, eblk, bbase);
    k_bscatter<<<eblk, 256, 0, stream>>>(src, dst, E, blkcnt, pairs);
    k_bbuild<<<nb, 256, 0, stream>>>(pairs, bbase, N, rowptr, csr);

    for (int l = 0; l < NLAYERS; ++l) {
        const ushort* hin = (l == 0) ? xb : hb[l - 1];
        const float* psl    = (l == 0) ? nullptr : (sliced + (l - 1) * 256);
        const float* grow_  = gamma + (l == 0 ? 0 : (l - 1)) * HID;
        const float* brow_  = beta  + (l == 0 ? 0 : (l - 1)) * HID;

        k_agg<<<(N + 15) / 16, 256, 0, stream>>>(
            rowptr, csr, (const uint2*)hin, psl, grow_, brow_, epsg, l, z0buf, N);

        k_mlp_dense<<<(N + 63) / 64, 256, 0, stream>>>(
            (const uint4*)z0buf, l, batch,
            w1h + (size_t)l * 16384, w1l + (size_t)l * 16384, b1 + l * HID,
            w2h + (size_t)l * 16384, w2l + (size_t)l * 16384, b2 + l * HID,
            hb[l], sliced + l * 256, gsum, N);
    }

    k_mlp<<<NGRAPH, 256, 0, stream>>>(gcnt, N, gsum, sliced, gamma, beta,
                                      l1w, l1b, l2w, l2b, (float*)d_out);
}

// Round 13
// 489.060 us; speedup vs baseline: 1.2314x; 1.0585x over previous
//
#include <hip/hip_runtime.h>

#define HID 128
#define NGRAPH 512
#define NLAYERS 3
#define BN_EPS 1e-5f
#define NPB 256          // nodes per bucket (CSR build)
#define EB 4096          // edges per build block

typedef __attribute__((ext_vector_type(8))) short bf16x8;
typedef __attribute__((ext_vector_type(4))) float f32x4;
typedef __attribute__((ext_vector_type(2))) float f32x2;

__device__ inline unsigned short f2bf(float x) {
    union { float f; unsigned u; } v; v.f = x;
    unsigned r = v.u + 0x7FFFu + ((v.u >> 16) & 1u);
    return (unsigned short)(r >> 16);
}
__device__ inline float bf2f(unsigned short b) {
    union { float f; unsigned u; } v; v.u = ((unsigned)b) << 16; return v.f;
}
// 1 dword (2 packed bf16) -> f32x2 {lo, hi}
__device__ inline f32x2 bfp(unsigned u) {
    union { unsigned q; float f; } lo, hi;
    lo.q = u << 16; hi.q = u & 0xFFFF0000u;
    f32x2 r; r[0] = lo.f; r[1] = hi.f; return r;
}

// ---------------------------------------------------------------------------
// prep (one launch): W split+transpose | x->bf16 | ecount (+btot atomics)
// | graph-count histogram.  Zeroing of sliced/gsum/btot/gcnt via memset.
// ---------------------------------------------------------------------------
__global__ void k_prep(const float4* __restrict__ x4, ushort* __restrict__ xb, int total4,
                       const float* __restrict__ W1, ushort* __restrict__ w1h, ushort* __restrict__ w1l,
                       const float* __restrict__ W2, ushort* __restrict__ w2h, ushort* __restrict__ w2l,
                       int wtotal, int xblocks,
                       const int* __restrict__ dst, int E, int* __restrict__ blkcnt,
                       int* __restrict__ btot,
                       const int* __restrict__ batch, int N, int eblk, int* __restrict__ gcnt) {
    __shared__ int hist[512];
    int b = blockIdx.x, t = threadIdx.x;
    if (b < 384) {
        int gid = b * 256 + t;
        const float* W; ushort *Wh, *Wl; int e;
        if (gid < wtotal) { W = W1; Wh = w1h; Wl = w1l; e = gid; }
        else              { W = W2; Wh = w2h; Wl = w2l; e = gid - wtotal; }
        if (e < wtotal) {
            int l = e >> 14, rem = e & 16383, k = rem >> 7, n = rem & 127;
            float v = W[e];
            ushort hi = f2bf(v);
            ushort lo = f2bf(v - bf2f(hi));
            int o = (l << 14) + (n << 7) + k;
            Wh[o] = hi; Wl[o] = lo;
        }
    } else if (b < 384 + xblocks) {
        int i = (b - 384) * 256 + t;
        if (i < total4) {
            float4 v = x4[i];
            uint2 p;
            p.x = ((unsigned)f2bf(v.y) << 16) | f2bf(v.x);
            p.y = ((unsigned)f2bf(v.w) << 16) | f2bf(v.z);
            ((uint2*)xb)[i] = p;
        }
    } else if (b < 384 + xblocks + eblk) {
        // edge count histogram + bucket-total atomics (int, order-independent)
        int b2 = b - (384 + xblocks);
        hist[t] = 0; hist[t + 256] = 0;
        __syncthreads();
        int base = b2 * EB;
        #pragma unroll
        for (int i = 0; i < 16; ++i) {
            int e = base + i * 256 + t;
            if (e < E) atomicAdd(&hist[dst[e] >> 8], 1);
        }
        __syncthreads();
        blkcnt[b2 * 512 + t]       = hist[t];
        blkcnt[b2 * 512 + t + 256] = hist[t + 256];
        if (hist[t])       atomicAdd(&btot[t], hist[t]);
        if (hist[t + 256]) atomicAdd(&btot[t + 256], hist[t + 256]);
    } else {
        // per-graph node count histogram (4096 nodes per block)
        int b3 = b - (384 + xblocks + eblk);
        hist[t] = 0; hist[t + 256] = 0;
        __syncthreads();
        int base = b3 * 4096;
        #pragma unroll
        for (int i = 0; i < 16; ++i) {
            int n = base + i * 256 + t;
            if (n < N) atomicAdd(&hist[batch[n]], 1);
        }
        __syncthreads();
        if (hist[t])       atomicAdd(&gcnt[t], hist[t]);
        if (hist[t + 256]) atomicAdd(&gcnt[t + 256], hist[t + 256]);
    }
}

// ---------------------------------------------------------------------------
// CSR build.  R13: k_bscan merged into k_colscan — each block redundantly
// scans the 512-entry btot in LDS (parallel across blocks) to derive its own
// bbase[b]; removes the 1-block k_bscan and its full-device drain bubble.
// ---------------------------------------------------------------------------
__global__ __launch_bounds__(512) void k_colscan(int* __restrict__ blkcnt, int eblk,
                                                 const int* __restrict__ btot, int nb, int E,
                                                 int* __restrict__ bbase, int* __restrict__ rowptrN) {
    __shared__ int sh[512];
    __shared__ int bb;
    int t = threadIdx.x;
    int b = blockIdx.x;
    // phase 1: scan btot -> this block's bucket base
    sh[t] = (t < nb) ? btot[t] : 0;
    __syncthreads();
    #pragma unroll
    for (int s = 1; s < 512; s <<= 1) {
        int v = (t >= s) ? sh[t - s] : 0;
        __syncthreads();
        sh[t] += v;
        __syncthreads();
    }
    if (t == b) bb = (b == 0) ? 0 : sh[b - 1];
    __syncthreads();
    int base_b = bb;
    if (t == 0) bbase[b] = base_b;
    if (b == 0 && t == 0) { bbase[nb] = E; *rowptrN = E; }
    __syncthreads();
    // phase 2: scan this bucket's column of blkcnt
    sh[t] = (t < eblk) ? blkcnt[t * 512 + b] : 0;
    __syncthreads();
    #pragma unroll
    for (int s = 1; s < 512; s <<= 1) {
        int v = (t >= s) ? sh[t - s] : 0;
        __syncthreads();
        sh[t] += v;
        __syncthreads();
    }
    int excl = (t == 0) ? 0 : sh[t - 1];
    if (t < eblk) blkcnt[t * 512 + b] = base_b + excl;
}

__global__ __launch_bounds__(256) void k_bscatter(const int* __restrict__ src,
                                                  const int* __restrict__ dst, int E,
                                                  const int* __restrict__ blkcnt,
                                                  unsigned* __restrict__ pairs) {
    __shared__ int hist[512];    // local cursor (starts at 0)
    __shared__ int lbase[512];   // absolute base for this block's chunk per bucket
    int t = threadIdx.x;
    hist[t] = 0; hist[t + 256] = 0;
    lbase[t]       = blkcnt[blockIdx.x * 512 + t];
    lbase[t + 256] = blkcnt[blockIdx.x * 512 + t + 256];
    __syncthreads();
    int base = blockIdx.x * EB;
    #pragma unroll
    for (int i = 0; i < 16; ++i) {
        int e = base + i * 256 + t;
        if (e < E) {
            int d = dst[e];
            int b = d >> 8;
            int pos = lbase[b] + atomicAdd(&hist[b], 1);
            pairs[pos] = ((unsigned)(d & 255) << 24) | (unsigned)src[e];
        }
    }
}

__global__ __launch_bounds__(256) void k_bbuild(const unsigned* __restrict__ pairs,
                                                const int* __restrict__ bbase, int N,
                                                int* __restrict__ rowptr, int* __restrict__ csr) {
    __shared__ int cnt[256];
    __shared__ int off[256];
    int t = threadIdx.x;
    int b = blockIdx.x;
    int base = bbase[b], bcount = bbase[b + 1] - base;
    cnt[t] = 0;
    __syncthreads();
    for (int i = t; i < bcount; i += 256) atomicAdd(&cnt[pairs[base + i] >> 24], 1);
    __syncthreads();
    off[t] = cnt[t];
    __syncthreads();
    for (int s = 1; s < 256; s <<= 1) {
        int v = (t >= s) ? off[t - s] : 0;
        __syncthreads();
        off[t] += v;
        __syncthreads();
    }
    int excl = (t == 0) ? 0 : off[t - 1];
    int node = b * NPB + t;
    if (node < N) rowptr[node] = base + excl;
    cnt[t] = excl;                      // becomes per-node cursor
    __syncthreads();
    for (int i = t; i < bcount; i += 256) {
        unsigned p = pairs[base + i];
        int dl = p >> 24;
        int pos = base + atomicAdd(&cnt[dl], 1);
        csr[pos] = (int)(p & 0xFFFFFFu);
    }
}

// ---------------------------------------------------------------------------
// part 1: pure gather+BN -> z0.  (R9/R11 known-good config: (256,6), 40 VGPR,
// no spill.  R10's (256,8) spilled — do not raise.)
// ---------------------------------------------------------------------------
__global__ __launch_bounds__(256, 6) void k_agg(
        const int* __restrict__ rowptr, const int* __restrict__ csr_src,
        const uint2* __restrict__ hinb,
        const float* __restrict__ prev_sliced,     // null for layer 0; else 8 slices (stride 768)
        const float* __restrict__ g_row, const float* __restrict__ be_row,
        const float* __restrict__ eps_gin, int layer,
        ushort* __restrict__ z0out, int N) {
    __shared__ float sfold[256];
    const int t = threadIdx.x;
    const int lane = t & 63;
    const int wv = t >> 6;
    const int q = lane >> 4;           // 0..3: row within the wave
    const int f = lane & 15;           // uint4 lane (8 bf16 features) within row

    if (prev_sliced) {
        float s = 0.f;
        #pragma unroll
        for (int k = 0; k < 8; ++k) s += prev_sliced[k * 768 + t];
        sfold[t] = s;                  // sum[0..127] | sq[128..255]
        __syncthreads();
    }

    f32x2 scv2[4], shv2[4];
    if (prev_sliced) {
        float invn = 1.0f / (float)N;
        #pragma unroll
        for (int d = 0; d < 4; ++d) {
            #pragma unroll
            for (int h = 0; h < 2; ++h) {
                int fi = f * 8 + d * 2 + h;
                float mu = sfold[fi] * invn;
                float var = sfold[128 + fi] * invn - mu * mu;
                float inv = rsqrtf(var + BN_EPS);
                float scj = g_row[fi] * inv;
                scv2[d][h] = scj; shv2[d][h] = be_row[fi] - mu * scj;
            }
        }
    } else {
        #pragma unroll
        for (int d = 0; d < 4; ++d) { scv2[d] = (f32x2){1.f, 1.f}; shv2[d] = (f32x2){0.f, 0.f}; }
    }
    float e1 = 1.0f + eps_gin[layer];
    const uint4* hin4 = (const uint4*)hinb;

    int r = blockIdx.x * 16 + wv * 4 + q;     // global row
    f32x2 a2[4];
    #pragma unroll
    for (int d = 0; d < 4; ++d) a2[d] = (f32x2){0.f, 0.f};
    float cdeg = 0.f;
    if (r < N) {
        int beg = rowptr[r], end = rowptr[r + 1];
        uint4 hv = hin4[(size_t)r * 16 + f];
        a2[0] = e1 * bfp(hv.x); a2[1] = e1 * bfp(hv.y);
        a2[2] = e1 * bfp(hv.z); a2[3] = e1 * bfp(hv.w);
        int p = beg;
        // ---- full batches: NO masks ----
        for (; p + 8 <= end; p += 8) {
            int s0 = csr_src[p],     s1 = csr_src[p + 1], s2 = csr_src[p + 2], s3 = csr_src[p + 3];
            int s4 = csr_src[p + 4], s5 = csr_src[p + 5], s6 = csr_src[p + 6], s7 = csr_src[p + 7];
            uint4 v0 = hin4[(size_t)s0 * 16 + f];
            uint4 v1 = hin4[(size_t)s1 * 16 + f];
            uint4 v2 = hin4[(size_t)s2 * 16 + f];
            uint4 v3 = hin4[(size_t)s3 * 16 + f];
            uint4 v4 = hin4[(size_t)s4 * 16 + f];
            uint4 v5 = hin4[(size_t)s5 * 16 + f];
            uint4 v6 = hin4[(size_t)s6 * 16 + f];
            uint4 v7 = hin4[(size_t)s7 * 16 + f];
            a2[0] += ((bfp(v0.x) + bfp(v1.x)) + (bfp(v2.x) + bfp(v3.x)))
                   + ((bfp(v4.x) + bfp(v5.x)) + (bfp(v6.x) + bfp(v7.x)));
            a2[1] += ((bfp(v0.y) + bfp(v1.y)) + (bfp(v2.y) + bfp(v3.y)))
                   + ((bfp(v4.y) + bfp(v5.y)) + (bfp(v6.y) + bfp(v7.y)));
            a2[2] += ((bfp(v0.z) + bfp(v1.z)) + (bfp(v2.z) + bfp(v3.z)))
                   + ((bfp(v4.z) + bfp(v5.z)) + (bfp(v6.z) + bfp(v7.z)));
            a2[3] += ((bfp(v0.w) + bfp(v1.w)) + (bfp(v2.w) + bfp(v3.w)))
                   + ((bfp(v4.w) + bfp(v5.w)) + (bfp(v6.w) + bfp(v7.w)));
        }
        // ---- single partial tail: clamp + dword-level masks ----
        if (p < end) {
            int last = end - 1;
            int c1 = min(p + 1, last), c2 = min(p + 2, last), c3 = min(p + 3, last);
            int c4 = min(p + 4, last), c5 = min(p + 5, last), c6 = min(p + 6, last);
            int s0 = csr_src[p],  s1 = csr_src[c1], s2 = csr_src[c2], s3 = csr_src[c3];
            int s4 = csr_src[c4], s5 = csr_src[c5], s6 = csr_src[c6];
            uint4 v0 = hin4[(size_t)s0 * 16 + f];
            uint4 v1 = hin4[(size_t)s1 * 16 + f];
            uint4 v2 = hin4[(size_t)s2 * 16 + f];
            uint4 v3 = hin4[(size_t)s3 * 16 + f];
            uint4 v4 = hin4[(size_t)s4 * 16 + f];
            uint4 v5 = hin4[(size_t)s5 * 16 + f];
            uint4 v6 = hin4[(size_t)s6 * 16 + f];
            int rem = end - p;           // 1..7
            unsigned m1 = (rem > 1) ? 0xFFFFFFFFu : 0u;
            unsigned m2 = (rem > 2) ? 0xFFFFFFFFu : 0u;
            unsigned m3 = (rem > 3) ? 0xFFFFFFFFu : 0u;
            unsigned m4 = (rem > 4) ? 0xFFFFFFFFu : 0u;
            unsigned m5 = (rem > 5) ? 0xFFFFFFFFu : 0u;
            unsigned m6 = (rem > 6) ? 0xFFFFFFFFu : 0u;
            a2[0] += ((bfp(v0.x) + bfp(v1.x & m1)) + (bfp(v2.x & m2) + bfp(v3.x & m3)))
                   + ((bfp(v4.x & m4) + bfp(v5.x & m5)) + bfp(v6.x & m6));
            a2[1] += ((bfp(v0.y) + bfp(v1.y & m1)) + (bfp(v2.y & m2) + bfp(v3.y & m3)))
                   + ((bfp(v4.y & m4) + bfp(v5.y & m5)) + bfp(v6.y & m6));
            a2[2] += ((bfp(v0.z) + bfp(v1.z & m1)) + (bfp(v2.z & m2) + bfp(v3.z & m3)))
                   + ((bfp(v4.z & m4) + bfp(v5.z & m5)) + bfp(v6.z & m6));
            a2[3] += ((bfp(v0.w) + bfp(v1.w & m1)) + (bfp(v2.w & m2) + bfp(v3.w & m3)))
                   + ((bfp(v4.w & m4) + bfp(v5.w & m5)) + bfp(v6.w & m6));
        }
        cdeg = e1 + (float)(end - beg);
    }
    f32x2 rr2[4];
    #pragma unroll
    for (int d = 0; d < 4; ++d) rr2[d] = scv2[d] * a2[d] + cdeg * shv2[d];
    uint4 ph;
    ph.x = ((unsigned)f2bf(rr2[0][1]) << 16) | f2bf(rr2[0][0]);
    ph.y = ((unsigned)f2bf(rr2[1][1]) << 16) | f2bf(rr2[1][0]);
    ph.z = ((unsigned)f2bf(rr2[2][1]) << 16) | f2bf(rr2[2][0]);
    ph.w = ((unsigned)f2bf(rr2[3][1]) << 16) | f2bf(rr2[3][0]);
    if (r < N) ((uint4*)z0out)[(size_t)r * 16 + f] = ph;
}

// ---------------------------------------------------------------------------
// part 2: dense MLP over z0.  R13: PERSISTENT grid re-added (512 blocks =
// 2/CU, tiles strided) — R10-R12 decomposition showed it was a ~7 us/layer
// win (weights hoisted ONCE per block, reused across ~3 tiles) that was
// reverted with the round.  launch_bounds(256,2).
// ---------------------------------------------------------------------------
__global__ __launch_bounds__(256, 2) void k_mlp_dense(
        const uint4* __restrict__ z0, int layer, const int* __restrict__ batch,
        const ushort* __restrict__ w1h, const ushort* __restrict__ w1l,
        const float* __restrict__ b1,
        const ushort* __restrict__ w2h, const ushort* __restrict__ w2l,
        const float* __restrict__ b2,
        ushort* __restrict__ Hout, float* __restrict__ stat_sl,
        float* __restrict__ gsum, int N, int ntiles) {
    __shared__ __align__(16) ushort smem[8192];    // 16 KB
    const int t = threadIdx.x;
    const int lane = t & 63;
    const int wv = t >> 6;
    const int li = lane & 15;
    const int kq = lane >> 4;
    const int n0 = wv * 32;
    const int swz = (li & 7) * 4;

    // ---- hoist all weight fragments into registers (32 x 16B loads, once) ----
    bf16x8 w1hr[8], w1lr[8], w2hr[8], w2lr[8];
    #pragma unroll
    for (int ch = 0; ch < 2; ++ch)
        #pragma unroll
        for (int ks = 0; ks < 2; ++ks)
            #pragma unroll
            for (int nt = 0; nt < 2; ++nt) {
                int i = ch * 4 + ks * 2 + nt;
                size_t wo = (size_t)(n0 + nt * 16 + li) * 128 + (ch * 64 + ks * 32 + kq * 8);
                w1hr[i] = *(const bf16x8*)&w1h[wo];
                w1lr[i] = *(const bf16x8*)&w1l[wo];
                w2hr[i] = *(const bf16x8*)&w2h[wo];
                w2lr[i] = *(const bf16x8*)&w2l[wo];
            }
    float bz0 = b1[n0 + li], bz1 = b1[n0 + 16 + li];
    float bb0 = b2[n0 + li], bb1 = b2[n0 + 16 + li];

    for (int tile = blockIdx.x; tile < ntiles; tile += gridDim.x) {
        const int row0 = tile * 64;

        // ---- stage z0 tile -> LDS (swizzled), zero-fill rows >= N ----
        {
            const uint4 zz = {0u, 0u, 0u, 0u};
            #pragma unroll
            for (int i = 0; i < 4; ++i) {
                int idx = i * 256 + t;             // 0..1023
                int r = idx >> 4, f = idx & 15;
                uint4 v = (row0 + r < N) ? z0[(size_t)(row0 + r) * 16 + f] : zz;
                ((uint4*)smem)[r * 16 + (f ^ (r & 7))] = v;
            }
        }
        __syncthreads();

        f32x4 acc[4][2];
        #pragma unroll
        for (int i = 0; i < 4; ++i) {
            acc[i][0] = (f32x4){0.f, 0.f, 0.f, 0.f};
            acc[i][1] = (f32x4){0.f, 0.f, 0.f, 0.f};
        }

        // ---------------- GEMM1: z1 = z0 @ W1 (registers only for W) ----------------
        #pragma unroll
        for (int ch = 0; ch < 2; ++ch) {
            #pragma unroll
            for (int ks = 0; ks < 2; ++ks) {
                int kcol = ch * 8 + ks * 4 + kq;            // u4 col 0..15
                #pragma unroll
                for (int mt = 0; mt < 4; ++mt) {
                    int r = mt * 16 + li;
                    int hw = (r * 16 + (kcol ^ (li & 7))) * 8;
                    bf16x8 ah = *(const bf16x8*)&smem[hw];
                    #pragma unroll
                    for (int nt = 0; nt < 2; ++nt) {
                        int i = ch * 4 + ks * 2 + nt;
                        acc[mt][nt] = __builtin_amdgcn_mfma_f32_16x16x32_bf16(ah, w1hr[i], acc[mt][nt], 0, 0, 0);
                        acc[mt][nt] = __builtin_amdgcn_mfma_f32_16x16x32_bf16(ah, w1lr[i], acc[mt][nt], 0, 0, 0);
                    }
                }
            }
        }

        // ---- z1 = relu(acc + b1) -> Z overlay (A-layout, bf16, swizzled) ----
        __syncthreads();                    // all GEMM1 A-reads done before overwrite
        #pragma unroll
        for (int mt = 0; mt < 4; ++mt) {
            #pragma unroll
            for (int nt = 0; nt < 2; ++nt) {
                int c = n0 + nt * 16 + li;
                int dk = c >> 1;
                int halfbase = (dk >> 5) * 32;
                int dlow = dk & 31;
                int codd = c & 1;
                float bias = nt ? bz1 : bz0;
                #pragma unroll
                for (int reg = 0; reg < 4; ++reg) {
                    int r = mt * 16 + kq * 4 + reg;
                    float v = fmaxf(acc[mt][nt][reg] + bias, 0.f);
                    int us = (r * 64 + halfbase + (dlow ^ ((r & 7) * 4))) * 2 + codd;
                    smem[us] = f2bf(v);
                }
            }
        }
        #pragma unroll
        for (int i = 0; i < 4; ++i) {
            acc[i][0] = (f32x4){0.f, 0.f, 0.f, 0.f};
            acc[i][1] = (f32x4){0.f, 0.f, 0.f, 0.f};
        }
        __syncthreads();

        // ---------------- GEMM2: z2 = z1 @ W2 (registers only for W) ----------------
        #pragma unroll
        for (int ch = 0; ch < 2; ++ch) {
            #pragma unroll
            for (int ks = 0; ks < 2; ++ks) {
                int aoff = (ks * 16 + kq * 4) ^ swz;        // dwords
                #pragma unroll
                for (int mt = 0; mt < 4; ++mt) {
                    int idx = ((mt * 16 + li) * 64 + ch * 32 + aoff) * 2;
                    bf16x8 ah = *(const bf16x8*)&smem[idx];
                    #pragma unroll
                    for (int nt = 0; nt < 2; ++nt) {
                        int i = ch * 4 + ks * 2 + nt;
                        acc[mt][nt] = __builtin_amdgcn_mfma_f32_16x16x32_bf16(ah, w2hr[i], acc[mt][nt], 0, 0, 0);
                        acc[mt][nt] = __builtin_amdgcn_mfma_f32_16x16x32_bf16(ah, w2lr[i], acc[mt][nt], 0, 0, 0);
                    }
                }
            }
        }

        // ---- epilogue: bias+relu; z2 -> LDS (row-major); BN stats; pool sums ----
        int btr[4][4];
        #pragma unroll
        for (int mt = 0; mt < 4; ++mt)
            #pragma unroll
            for (int reg = 0; reg < 4; ++reg) {
                int grow = row0 + mt * 16 + kq * 4 + reg;
                btr[mt][reg] = (grow < N) ? batch[grow] : -1;
            }
        __syncthreads();                    // all GEMM2 z1-reads done before overwrite
        float s0 = 0.f, q0 = 0.f, s1 = 0.f, q1 = 0.f;
        #pragma unroll
        for (int mt = 0; mt < 4; ++mt) {
            #pragma unroll
            for (int reg = 0; reg < 4; ++reg) {
                int r = mt * 16 + kq * 4 + reg;
                float v0 = fmaxf(acc[mt][0][reg] + bb0, 0.f);
                float v1 = fmaxf(acc[mt][1][reg] + bb1, 0.f);
                smem[r * 128 + n0 + li]      = f2bf(v0);
                smem[r * 128 + n0 + 16 + li] = f2bf(v1);
                if (btr[mt][reg] >= 0) {
                    s0 += v0; q0 += v0 * v0; s1 += v1; q1 += v1 * v1;
                }
            }
        }
        __syncthreads();
        // coalesced store: 64 rows x 16 uint4 (full 64B lines)
        {
            int valid = N - row0; if (valid > 64) valid = 64;
            int tot = valid * 16;
            for (int i = t; i < tot; i += 256) {
                int r = i >> 4, c = i & 15;
                ((uint4*)&Hout[(size_t)(row0 + r) * HID])[c] = ((const uint4*)smem)[r * 16 + c];
            }
        }
        s0 += __shfl_xor(s0, 16); s0 += __shfl_xor(s0, 32);
        q0 += __shfl_xor(q0, 16); q0 += __shfl_xor(q0, 32);
        s1 += __shfl_xor(s1, 16); s1 += __shfl_xor(s1, 32);
        q1 += __shfl_xor(q1, 16); q1 += __shfl_xor(q1, 32);
        if (kq == 0) {
            float* ss = stat_sl + (blockIdx.x & 7) * 768;   // slice: sum[0..127] | sq[128..255]
            unsafeAtomicAdd(&ss[n0 + li], s0);
            unsafeAtomicAdd(&ss[128 + n0 + li], q0);
            unsafeAtomicAdd(&ss[n0 + 16 + li], s1);
            unsafeAtomicAdd(&ss[128 + n0 + 16 + li], q1);
        }
        // per-graph raw sums (affine applied later in k_mlp)
        int lastr = N - 1; if (lastr > row0 + 63) lastr = row0 + 63;
        int g_lo = batch[row0], g_hi = batch[lastr];
        int loff = layer * HID;
        for (int g = g_lo; g <= g_hi; ++g) {
            float p0 = 0.f, p1 = 0.f;
            #pragma unroll
            for (int mt = 0; mt < 4; ++mt)
                #pragma unroll
                for (int reg = 0; reg < 4; ++reg) {
                    if (btr[mt][reg] == g) {
                        p0 += fmaxf(acc[mt][0][reg] + bb0, 0.f);
                        p1 += fmaxf(acc[mt][1][reg] + bb1, 0.f);
                    }
                }
            p0 += __shfl_xor(p0, 16); p0 += __shfl_xor(p0, 32);
            p1 += __shfl_xor(p1, 16); p1 += __shfl_xor(p1, 32);
            if (kq == 0) {
                unsafeAtomicAdd(&gsum[(size_t)g * 384 + loff + n0 + li], p0);
                unsafeAtomicAdd(&gsum[(size_t)g * 384 + loff + n0 + 16 + li], p1);
            }
        }
        __syncthreads();   // smem fully consumed before next tile's stage
    }
}

// ---------------------------------------------------------------------------
// final MLP — 512 blocks (1 graph each) x 256 thr; no binary searches;
// gl staged cooperatively with inline 8-slice BN fold; split-k GEMM1;
// head via wave-0 shuffle reduction.  (R12-verified, ~8 us)
// ---------------------------------------------------------------------------
__global__ __launch_bounds__(256) void k_mlp(const int* __restrict__ gcnt, int N,
                     const float* __restrict__ gsum, const float* __restrict__ sliced,
                     const float* __restrict__ gamma, const float* __restrict__ beta,
                     const float* __restrict__ w1, const float* __restrict__ b1,
                     const float* __restrict__ w2, const float* __restrict__ b2,
                     float* __restrict__ out) {
    __shared__ float gl[384];
    __shared__ float ph[2][128];
    __shared__ float hh[128];
    int g = blockIdx.x, t = threadIdx.x;
    float cnt = (float)gcnt[g];
    float invc = 1.0f / fmaxf(cnt, 1.0f);
    float invn = 1.0f / (float)N;
    for (int i = t; i < 384; i += 256) {
        int l = i >> 7, f = i & 127;
        float sum_ = 0.f, sq_ = 0.f;
        #pragma unroll
        for (int k = 0; k < 8; ++k) {
            sum_ += sliced[k * 768 + l * 256 + f];
            sq_  += sliced[k * 768 + l * 256 + 128 + f];
        }
        float mu = sum_ * invn;
        float var = sq_ * invn - mu * mu;
        float inv = rsqrtf(var + BN_EPS);
        float sc = gamma[l * HID + f] * inv;
        float sh = beta[l * HID + f] - mu * sc;
        gl[i] = (gsum[(size_t)g * 384 + i] * sc + sh * cnt) * invc;
    }
    __syncthreads();
    int f = t & 127, kh = t >> 7;
    float acc = kh ? 0.f : b1[f];
    for (int k = kh * 192; k < kh * 192 + 192; ++k)
        acc = fmaf(gl[k], w1[k * HID + f], acc);
    ph[kh][f] = acc;
    __syncthreads();
    if (t < 128) hh[t] = fmaxf(ph[0][t] + ph[1][t], 0.f);
    __syncthreads();
    if (t < 64) {
        float h0 = hh[t], h1 = hh[t + 64];
        float p[10];
        #pragma unroll
        for (int o = 0; o < 10; ++o)
            p[o] = h0 * w2[t * 10 + o] + h1 * w2[(t + 64) * 10 + o];
        #pragma unroll
        for (int o = 0; o < 10; ++o) {
            #pragma unroll
            for (int s = 32; s > 0; s >>= 1) p[o] += __shfl_xor(p[o], s);
        }
        if (t == 0) {
            #pragma unroll
            for (int o = 0; o < 10; ++o) out[g * 10 + o] = b2[o] + p[o];
        }
    }
}

// ---------------------------------------------------------------------------
extern "C" void kernel_launch(void* const* d_in, const int* in_sizes, int n_in,
                              void* d_out, int out_size, void* d_ws, size_t ws_size,
                              hipStream_t stream) {
    const float* x     = (const float*)d_in[0];
    const int*   ei    = (const int*)d_in[1];
    const int*   batch = (const int*)d_in[2];
    const float* W1    = (const float*)d_in[3];
    const float* b1    = (const float*)d_in[4];
    const float* W2    = (const float*)d_in[5];
    const float* b2    = (const float*)d_in[6];
    const float* gamma = (const float*)d_in[7];
    const float* beta  = (const float*)d_in[8];
    const float* epsg  = (const float*)d_in[9];
    const float* l1w   = (const float*)d_in[10];
    const float* l1b   = (const float*)d_in[11];
    const float* l2w   = (const float*)d_in[12];
    const float* l2b   = (const float*)d_in[13];

    const int N = in_sizes[0] / HID;
    const int E = in_sizes[1] / 2;
    const int* src = ei;
    const int* dst = ei + E;
    const int nb = (N + NPB - 1) / NPB;           // <= 512
    const int eblk = (E + EB - 1) / EB;           // <= 512

    float* w = (float*)d_ws;
    const size_t NF = (size_t)N * HID;
    ushort* xb    = (ushort*)(w + NF);                       // x as bf16 (NF ushorts)
    ushort* hb[3] = { xb + NF, xb + 2 * NF, xb + 3 * NF };   // layer outputs, bf16
    ushort* z0buf = xb + 4 * NF;                             // aggregated input (NF ushorts)
    float* sliced = w + 4 * NF;       // 8 slices x 3 layers x 256 = 6144
    float* gsum   = sliced + 6144;    // 512 * 384 = 196608
    int*   btot   = (int*)(gsum + (size_t)NGRAPH * 384);     // 513
    int*   gcnt   = btot + 513;                              // 512
    int*   rowptr = gcnt + 512;                              // N + 1
    int*   csr    = rowptr + N + 1;                          // E
    int*   bbase  = csr + E;                                 // nb + 2
    ushort* wt  = (ushort*)(((uintptr_t)(bbase + nb + 2) + 15) & ~(uintptr_t)15);
    ushort* w1h = wt;
    ushort* w1l = wt + 49152;
    ushort* w2h = wt + 98304;
    ushort* w2l = wt + 147456;

    unsigned* pairs  = (unsigned*)w;                // E uints (CSR build only)
    int*      blkcnt = (int*)(w + 2 * 1024 * 1024); // eblk*512 (CSR build only)

    // zero sliced + gsum + btot + gcnt in one stream-ordered memset
    hipMemsetAsync(sliced, 0, (6144 + (size_t)NGRAPH * 384 + 513 + 512) * sizeof(float), stream);

    const int total4 = (int)(NF / 4);
    const int xblocks = (total4 + 255) / 256;
    const int gblocks = (N + 4095) / 4096;
    const int prep_blocks = 384 + xblocks + eblk + gblocks;
    k_prep<<<prep_blocks, 256, 0, stream>>>((const float4*)x, xb, total4,
                                            W1, w1h, w1l, W2, w2h, w2l, NLAYERS * HID * HID,
                                            xblocks, dst, E, blkcnt, btot,
                                            batch, N, eblk, gcnt);

    // ---- build CSR ----
    k_colscan<<<nb, 512, 0, stream>>>(blkcnt, eblk, btot, nb, E, bbase, rowptr + N);
    k_bscatter<<<eblk, 256, 0, stream>>>(src, dst, E, blkcnt, pairs);
    k_bbuild<<<nb, 256, 0, stream>>>(pairs, bbase, N, rowptr, csr);

    const int ntiles = (N + 63) / 64;
    for (int l = 0; l < NLAYERS; ++l) {
        const ushort* hin = (l == 0) ? xb : hb[l - 1];
        const float* psl    = (l == 0) ? nullptr : (sliced + (l - 1) * 256);
        const float* grow_  = gamma + (l == 0 ? 0 : (l - 1)) * HID;
        const float* brow_  = beta  + (l == 0 ? 0 : (l - 1)) * HID;

        k_agg<<<(N + 15) / 16, 256, 0, stream>>>(
            rowptr, csr, (const uint2*)hin, psl, grow_, brow_, epsg, l, z0buf, N);

        k_mlp_dense<<<512, 256, 0, stream>>>(
            (const uint4*)z0buf, l, batch,
            w1h + (size_t)l * 16384, w1l + (size_t)l * 16384, b1 + l * HID,
            w2h + (size_t)l * 16384, w2l + (size_t)l * 16384, b2 + l * HID,
            hb[l], sliced + l * 256, gsum, N, ntiles);
    }

    k_mlp<<<NGRAPH, 256, 0, stream>>>(gcnt, N, gsum, sliced, gamma, beta,
                                      l1w, l1b, l2w, l2b, (float*)d_out);
}